// Round 7
// baseline (251.954 us; speedup 1.0000x reference)
//
#include <hip/hip_runtime.h>
#include <math.h>

#define BB 2
#define TT 12
#define NN 325
#define DD 64
#define HH 8
#define MM 3
#define NT (BB*TT*NN)   // 7800
#define NT64 (NT*64)
#define EPS 1e-6f
#define KTOT 4160       // 64*64 + 64 (bias fold)
#define SEGS 8
#define KPS 41          // 8*41 = 328
#define NR 328

typedef _Float16 f16x8 __attribute__((ext_vector_type(8)));
typedef _Float16 f16x2 __attribute__((ext_vector_type(2)));
typedef float f32x4 __attribute__((ext_vector_type(4)));
typedef float f32x2 __attribute__((ext_vector_type(2)));

#if __has_builtin(__builtin_amdgcn_exp2f)
#define EXP2F(x) __builtin_amdgcn_exp2f(x)
#else
#define EXP2F(x) exp2f(x)
#endif

__device__ inline float wave_reduce_sum(float v) {
    #pragma unroll
    for (int o = 32; o > 0; o >>= 1) v += __shfl_xor(v, o, 64);
    return v;
}

// ---------------- merged one-time prep:
//  blocks [0,780):   W2+b2 -> Wt[p][e][kk] f16 (K-major); p = bx/65, kk0 = (bx%65)*64
//  blocks [780,792): W1 transpose -> W1f
//  blocks [792,823): 8-seg mask words -> pmr
__global__ __launch_bounds__(256)
void prep_all(const float* __restrict__ mW2, const float* __restrict__ mb2,
              _Float16* __restrict__ Wt,
              const float* __restrict__ mW1, _Float16* __restrict__ W1f,
              const int* __restrict__ tms, unsigned* __restrict__ pmr) {
    const int bx = blockIdx.x;
    const int tid = threadIdx.x;
    if (bx < 780) {
        const int p = bx / 65;
        const int kk0 = (bx % 65) * 64;
        __shared__ float s[64][65];
        #pragma unroll
        for (int pass = 0; pass < 16; ++pass) {
            int idx = pass*256 + tid;
            int kl = idx >> 6, e = idx & 63;
            int kk = kk0 + kl;
            float v = (kk < 4096) ? mW2[(size_t)p*262144 + (size_t)kk*64 + e]
                                  : mb2[(size_t)p*4096 + (size_t)(kk-4096)*64 + e];
            s[kl][e] = v;
        }
        __syncthreads();
        #pragma unroll
        for (int pass = 0; pass < 16; ++pass) {
            int idx = pass*256 + tid;
            int e = idx >> 6, kl = idx & 63;
            Wt[(size_t)p*64*KTOT + (size_t)e*KTOT + kk0 + kl] = (_Float16)s[kl][e];
        }
        return;
    }
    if (bx < 792) {
        const int p = bx - 780;
        #pragma unroll
        for (int i = 0; i < 16; ++i) {
            int idx = i*256 + tid;
            int d = idx >> 6, e = idx & 63;
            W1f[(size_t)p*4096 + e*64 + d] = (_Float16)mW1[(size_t)p*4096 + d*64 + e];
        }
        return;
    }
    int idx = (bx - 792)*256 + tid;
    if (idx >= MM*NN*SEGS) return;
    int seg = idx & 7;
    int nq = (idx >> 3) % NN;
    int i = idx / (SEGS*NN);
    int ks = seg*KPS;
    int ke = (ks + KPS < NN) ? ks + KPS : NN;
    const int* row = tms + ((size_t)i*NN + nq)*NN;
    unsigned w0 = 0, w1 = 0;
    for (int k = ks; k < ke; ++k) {
        int b = k - ks;
        unsigned bit = (row[k] > 0) ? 1u : 0u;
        if (b < 32) w0 |= bit << b; else w1 |= bit << (b - 32);
    }
    pmr[(size_t)idx*2]     = w0;
    pmr[(size_t)idx*2 + 1] = w1;
}

// ---------------- meta GEMM v12: v9 tile structure (4 waves, 2M x 2N, 32x32 wave
// tile, dual reuse-2) + ring-3 staging with ONE barrier per K-iteration (was 2).
// Barrier at iter i+1 separates COMPUTE(i) [reads slot i%3] from STAGE(i+3)
// [writes slot (i+3)%3 = i%3]. Outstanding loads stay 8 (vmcnt(4) steady).
// LDS 72.5KB -> 2 blocks/CU. Loop = 2 x 12-unroll + static tail (lcm(3,4)=12)
// so all slot/ci indices are compile-time. grid (122,3). ----------------
template<int MODE>
__global__ __launch_bounds__(256, 2)
void meta_gemm_t(const float* __restrict__ x0, const float* __restrict__ x1,
                 const float* __restrict__ x2,
                 const float* __restrict__ s0, const float* __restrict__ s1,
                 const float* __restrict__ s2,
                 const _Float16* __restrict__ W1f, const float* __restrict__ b1m,
                 const _Float16* __restrict__ Wtm,
                 void* __restrict__ o0, void* __restrict__ o1, void* __restrict__ o2) {
    const int br = blockIdx.y;
    const int t0 = blockIdx.x * 64;
    const float* xg = (br==0) ? x0 : (br==1) ? x1 : x2;
    const float* sg = (br==0) ? s0 : (br==1) ? s1 : s2;
    const _Float16* W1b = W1f + (size_t)br*4096;
    const float* b1g = b1m + (size_t)br*64;
    const _Float16* W = Wtm + (size_t)br*64*KTOT;
    void* outp = (br==0) ? o0 : (br==1) ? o1 : o2;

    __shared__ _Float16 sx[64*64];      // 8 KB
    __shared__ _Float16 ss[64*64];      // 8 KB
    __shared__ _Float16 shT[64*68];     // 8.5 KB, [t][c] stride 68
    __shared__ _Float16 bB[3][1024*8];  // 3 x 16KB ring, each = 2 K-steps of 64

    const int tid = threadIdx.x;
    // stage x/ste: 512 16B-units, 2 per thread
    #pragma unroll
    for (int i = 0; i < 2; ++i) {
        int idx = i*256 + tid;
        int row = idx >> 3, u = idx & 7;
        int t = t0 + row;
        int boff = row*128 + ((u*16) ^ ((row & 7) << 4));
        f16x8 xo, so;
        if (t < NT) {
            const float4* xp = (const float4*)(xg + (size_t)t*64 + u*8);
            float4 a = xp[0], b = xp[1];
            f16x8 xv = {(_Float16)a.x,(_Float16)a.y,(_Float16)a.z,(_Float16)a.w,
                        (_Float16)b.x,(_Float16)b.y,(_Float16)b.z,(_Float16)b.w};
            const float4* sp = (const float4*)(sg + (size_t)t*64 + u*8);
            float4 c = sp[0], d = sp[1];
            f16x8 sv = {(_Float16)c.x,(_Float16)c.y,(_Float16)c.z,(_Float16)c.w,
                        (_Float16)d.x,(_Float16)d.y,(_Float16)d.z,(_Float16)d.w};
            xo = xv; so = sv;
        } else {
            f16x8 z = {(_Float16)0.f,(_Float16)0.f,(_Float16)0.f,(_Float16)0.f,
                       (_Float16)0.f,(_Float16)0.f,(_Float16)0.f,(_Float16)0.f};
            xo = z; so = z;
        }
        *(f16x8*)((char*)sx + boff) = xo;
        *(f16x8*)((char*)ss + boff) = so;
    }
    __syncthreads();

    const int wid = tid >> 6, lane = tid & 63;
    const int col = lane & 15, g = lane >> 4;
    const int wm = wid & 1, wn = wid >> 1;          // 2M x 2N, wave tile 32x32
    const int trow0 = wm*32 + col;
    const int trow1 = trow0 + 16;
    const int rb0 = trow0*128, rb1 = trow1*128;
    const int sz = (trow0 & 7) << 4;

    // ---- h-phase: all 4 waves compute h for tokens wid*16..+15, store shT[t][c] ----
    {
        const int hrow = wid*16 + col;
        const int hrb = hrow*128;
        const int hsz = (hrow & 7) << 4;
        f32x4 ha[4] = {{0,0,0,0},{0,0,0,0},{0,0,0,0},{0,0,0,0}};
        #pragma unroll
        for (int ph = 0; ph < 2; ++ph) {
            int dd = ph*32 + g*8;
            f16x8 sv = *(f16x8*)((char*)ss + hrb + ((dd*2) ^ hsz));
            #pragma unroll
            for (int ni = 0; ni < 4; ++ni) {
                f16x8 bw = *(const f16x8*)(W1b + (size_t)(ni*16+col)*64 + dd);
                ha[ni] = __builtin_amdgcn_mfma_f32_16x16x32_f16(sv, bw, ha[ni], 0, 0, 0);
            }
        }
        #pragma unroll
        for (int ni = 0; ni < 4; ++ni) {
            float bv = b1g[ni*16+col];
            #pragma unroll
            for (int r = 0; r < 4; ++r)
                shT[(wid*16 + g*4 + r)*68 + ni*16 + col] = (_Float16)fmaxf(ha[ni][r] + bv, 0.f);
        }
    }

    // ---- hoisted K-invariant x fragments (two M-tiles per wave) ----
    f16x8 xv00 = *(f16x8*)((char*)sx + rb0 + (((g*8)*2) ^ sz));
    f16x8 xv01 = *(f16x8*)((char*)sx + rb0 + (((32 + g*8)*2) ^ sz));
    f16x8 xv10 = *(f16x8*)((char*)sx + rb1 + (((g*8)*2) ^ sz));
    f16x8 xv11 = *(f16x8*)((char*)sx + rb1 + (((32 + g*8)*2) ^ sz));

    auto STAGE2 = [&](int slot, int st2) {   // stage K-steps 2*st2, 2*st2+1 (128 K); 4 loads/thread
        const _Float16* base = W + (size_t)st2*128;
        #pragma unroll
        for (int j = 0; j < 4; ++j) {
            int p = j*256 + tid;                // 0..1023
            int t = p >> 9;
            int rest = p & 511;
            int e = rest >> 3, wu = rest & 7;
            const _Float16* src = base + (size_t)t*64 + (size_t)e*KTOT + ((wu ^ (e & 7)) << 3);
            __builtin_amdgcn_global_load_lds(
                (const __attribute__((address_space(1))) void*)src,
                (__attribute__((address_space(3))) void*)&bB[slot][p*8],
                16, 0, 0);
        }
    };
    auto STAGE1 = [&](int slot, int st) {    // stage single K-step st (64 K); 2 loads/thread
        const _Float16* base = W + (size_t)st*64;
        #pragma unroll
        for (int j = 0; j < 2; ++j) {
            int p = j*256 + tid;                // 0..511
            int e = p >> 3, wu = p & 7;
            const _Float16* src = base + (size_t)e*KTOT + ((wu ^ (e & 7)) << 3);
            __builtin_amdgcn_global_load_lds(
                (const __attribute__((address_space(1))) void*)src,
                (__attribute__((address_space(3))) void*)&bB[slot][p*8],
                16, 0, 0);
        }
    };

    STAGE2(0, 0);
    STAGE2(1, 1);
    asm volatile("s_waitcnt lgkmcnt(0)" ::: "memory");   // drain own LDS ops (shT writes, xv reads)
    __builtin_amdgcn_sched_barrier(0);

    f32x4 A[2][2] = {{{0,0,0,0},{0,0,0,0}},{{0,0,0,0},{0,0,0,0}}};  // A[mt][nj]
    f16x8 hv0 = {}, hv1 = {};

    // K-invariant B-read addressing: two 16-col e-slices per wave
    const int e0 = wn*32 + col;
    const int e1 = e0 + 16;
    const int u00 = e0*8 + (g ^ (e0 & 7));
    const int u01 = e0*8 + ((4 + g) ^ (e0 & 7));
    const int u10 = e1*8 + (g ^ (e1 & 7));
    const int u11 = e1*8 + ((4 + g) ^ (e1 & 7));

    auto COMPUTE = [&](const _Float16* Bb, int ci) {   // ci compile-time at call sites
        #pragma unroll
        for (int t = 0; t < 2; ++t) {
            _Float16 hc0 = hv0[ci*2 + t];
            _Float16 hc1 = hv1[ci*2 + t];
            const _Float16* Bs = Bb + t*512*8;
            f16x8 b00 = *(const f16x8*)((const char*)Bs + u00*16);
            f16x8 b01 = *(const f16x8*)((const char*)Bs + u01*16);
            f16x8 b10 = *(const f16x8*)((const char*)Bs + u10*16);
            f16x8 b11 = *(const f16x8*)((const char*)Bs + u11*16);
            f16x8 p00 = xv00 * hc0;
            f16x8 p10 = xv10 * hc1;
            A[0][0] = __builtin_amdgcn_mfma_f32_16x16x32_f16(p00, b00, A[0][0], 0, 0, 0);
            A[0][1] = __builtin_amdgcn_mfma_f32_16x16x32_f16(p00, b10, A[0][1], 0, 0, 0);
            A[1][0] = __builtin_amdgcn_mfma_f32_16x16x32_f16(p10, b00, A[1][0], 0, 0, 0);
            A[1][1] = __builtin_amdgcn_mfma_f32_16x16x32_f16(p10, b10, A[1][1], 0, 0, 0);
            f16x8 p01 = xv01 * hc0;
            f16x8 p11 = xv11 * hc1;
            A[0][0] = __builtin_amdgcn_mfma_f32_16x16x32_f16(p01, b01, A[0][0], 0, 0, 0);
            A[0][1] = __builtin_amdgcn_mfma_f32_16x16x32_f16(p01, b11, A[0][1], 0, 0, 0);
            A[1][0] = __builtin_amdgcn_mfma_f32_16x16x32_f16(p11, b01, A[1][0], 0, 0, 0);
            A[1][1] = __builtin_amdgcn_mfma_f32_16x16x32_f16(p11, b11, A[1][1], 0, 0, 0);
        }
    };

    // Single-barrier ring-3 body for iteration i (slot/ci static via s):
    //   vmcnt(4): stage(i) complete (stage(i+1) in flight)
    //   barrier:  all waves done COMPUTE(i-1) -> slot (i+2)%3 free to overwrite
    //   STAGE(i+2) issued first (max load slack), then COMPUTE(i).
    // main: i = 0..23 as q(0..1) x s(0..11); 12 = lcm(3,4) keeps indices static.
    for (int q = 0; q < 2; ++q) {
        const int hb0 = trow0*68 + q*24;
        const int hb1 = trow1*68 + q*24;
        #pragma unroll
        for (int s = 0; s < 12; ++s) {
            asm volatile("s_waitcnt vmcnt(4)" ::: "memory");
            __builtin_amdgcn_sched_barrier(0);
            __builtin_amdgcn_s_barrier();
            if ((s & 3) == 0) {
                hv0 = *(f16x8*)&shT[hb0 + s*2];
                hv1 = *(f16x8*)&shT[hb1 + s*2];
            }
            STAGE2((s + 2) % 3, 12*q + s + 2);
            COMPUTE(bB[s % 3], s & 3);
        }
    }
    // tail: i = 24..29 (static)
    #pragma unroll
    for (int s = 24; s < 30; ++s) {
        asm volatile("s_waitcnt vmcnt(4)" ::: "memory");
        __builtin_amdgcn_sched_barrier(0);
        __builtin_amdgcn_s_barrier();
        if ((s & 3) == 0) {
            hv0 = *(f16x8*)&shT[trow0*68 + s*2];
            hv1 = *(f16x8*)&shT[trow1*68 + s*2];
        }
        STAGE2((s + 2) % 3, s + 2);          // stages 26..31
        COMPUTE(bB[s % 3], s & 3);
    }
    // i = 30: slot 0, ci 2; stage final single K-step into slot 2 (freed by barrier)
    asm volatile("s_waitcnt vmcnt(4)" ::: "memory");
    __builtin_amdgcn_sched_barrier(0);
    __builtin_amdgcn_s_barrier();
    STAGE1(2, 64);
    COMPUTE(bB[0], 2);
    // i = 31: slot 1, ci 3; outstanding = STAGE1's 2 loads
    asm volatile("s_waitcnt vmcnt(2)" ::: "memory");
    __builtin_amdgcn_sched_barrier(0);
    __builtin_amdgcn_s_barrier();
    COMPUTE(bB[1], 3);
    // final: bias fold from slot 2
    asm volatile("s_waitcnt vmcnt(0)" ::: "memory");
    __builtin_amdgcn_sched_barrier(0);
    __builtin_amdgcn_s_barrier();
    {
        // bias fold: A-operand = raw x (no h scale)
        const _Float16* Bs = bB[2];
        f16x8 b00 = *(const f16x8*)((const char*)Bs + u00*16);
        f16x8 b01 = *(const f16x8*)((const char*)Bs + u01*16);
        f16x8 b10 = *(const f16x8*)((const char*)Bs + u10*16);
        f16x8 b11 = *(const f16x8*)((const char*)Bs + u11*16);
        A[0][0] = __builtin_amdgcn_mfma_f32_16x16x32_f16(xv00, b00, A[0][0], 0, 0, 0);
        A[0][1] = __builtin_amdgcn_mfma_f32_16x16x32_f16(xv00, b10, A[0][1], 0, 0, 0);
        A[1][0] = __builtin_amdgcn_mfma_f32_16x16x32_f16(xv10, b00, A[1][0], 0, 0, 0);
        A[1][1] = __builtin_amdgcn_mfma_f32_16x16x32_f16(xv10, b10, A[1][1], 0, 0, 0);
        A[0][0] = __builtin_amdgcn_mfma_f32_16x16x32_f16(xv01, b01, A[0][0], 0, 0, 0);
        A[0][1] = __builtin_amdgcn_mfma_f32_16x16x32_f16(xv01, b11, A[0][1], 0, 0, 0);
        A[1][0] = __builtin_amdgcn_mfma_f32_16x16x32_f16(xv11, b01, A[1][0], 0, 0, 0);
        A[1][1] = __builtin_amdgcn_mfma_f32_16x16x32_f16(xv11, b11, A[1][1], 0, 0, 0);
    }

    if (MODE == 0) {
        float* op = (float*)outp;
        #pragma unroll
        for (int mt = 0; mt < 2; ++mt) {
            #pragma unroll
            for (int nj = 0; nj < 2; ++nj) {
                const int e = e0 + nj*16;
                #pragma unroll
                for (int r = 0; r < 4; ++r) {
                    int t = t0 + wm*32 + mt*16 + g*4 + r;
                    if (t < NT) op[(size_t)t*64 + e] = A[mt][nj][r];
                }
            }
        }
    } else {
        const float KSC = 0.35355339059327373f * 1.4426950408889634f;
        const float scl = (br == 1) ? KSC : 1.f;
        const int bt0 = t0 / NN;
        const int bound = (bt0 + 1)*NN;
        _Float16* op = (_Float16*)outp;
        #pragma unroll
        for (int mt = 0; mt < 2; ++mt) {
            #pragma unroll
            for (int nj = 0; nj < 2; ++nj) {
                const int e = e0 + nj*16;
                const int hh = e >> 3, dd = e & 7;
                #pragma unroll
                for (int r = 0; r < 4; ++r) {
                    int t = t0 + wm*32 + mt*16 + g*4 + r;
                    if (t < NT) {
                        int bt = (t >= bound) ? bt0 + 1 : bt0;
                        int n = t - bt*NN;
                        size_t pidx = ((size_t)(bt*8 + hh)*NR + n)*8 + dd;
                        op[pidx] = (_Float16)(A[mt][nj][r]*scl);
                    }
                }
            }
        }
    }
}

// ---------------- fused temporal attention + out-proj + residual + LN ----------------
__global__ __launch_bounds__(256)
void temporal_fused(const float* __restrict__ qg, const float* __restrict__ kg,
                    const float* __restrict__ vg, const float* __restrict__ xres,
                    const float* __restrict__ Wo, const float* __restrict__ gamma,
                    const float* __restrict__ beta, float* __restrict__ xout) {
    const int wid = threadIdx.x >> 6, lane = threadIdx.x & 63;
    const int token = blockIdx.x*4 + wid;
    if (token >= NT) return;
    const int n = token % NN;
    const int b = token / (NN*TT);
    const float scale = 0.35355339059327373f;
    const float qv = qg[(size_t)token*64 + lane] * scale;

    float s[TT], v[TT];
    #pragma unroll
    for (int kt = 0; kt < TT; ++kt) {
        size_t base = ((size_t)(b*TT + kt)*NN + n)*64 + lane;
        float kv = kg[base];
        v[kt] = vg[base];
        float d = qv * kv;
        d += __shfl_xor(d, 1, 64);
        d += __shfl_xor(d, 2, 64);
        d += __shfl_xor(d, 4, 64);
        s[kt] = d;
    }
    float m = s[0];
    #pragma unroll
    for (int kt = 1; kt < TT; ++kt) m = fmaxf(m, s[kt]);
    float l = 0.f, O = 0.f;
    #pragma unroll
    for (int kt = 0; kt < TT; ++kt) {
        float p = __expf(s[kt] - m);
        l += p;
        O += p * v[kt];
    }
    O /= l;
    float y = 0.f;
    #pragma unroll
    for (int d = 0; d < 64; ++d) y += __shfl(O, d, 64) * Wo[d*64 + lane];
    float r = xres[(size_t)token*64 + lane] + y;
    float mu = wave_reduce_sum(r) * (1.f/64.f);
    float diff = r - mu;
    float var = wave_reduce_sum(diff*diff) * (1.f/64.f);
    xout[(size_t)token*64 + lane] = diff * rsqrtf(var + EPS) * gamma[lane] + beta[lane];
}

// ---------------- spatial attention v13: interleaved KV LDS + register prefetch.
// 8-seg x 32q; grid (192, 11); lane = qu*8 + seg; 41 keys/seg. ----------------
__global__ __launch_bounds__(256)
void spatial_attn13(const _Float16* __restrict__ Qh, const _Float16* __restrict__ Kh,
                    const _Float16* __restrict__ Vh, const unsigned* __restrict__ pmr,
                    _Float16* __restrict__ outs) {
    const int bh = blockIdx.x;
    const int bt = bh >> 3, h = bh & 7;
    const int q0 = blockIdx.y * 32;
    __shared__ _Float16 KV[NR*16];    // [k][0:8)=K row, [k][8:16)=V row
    const int tid = threadIdx.x;
    const _Float16* Kb = Kh + (size_t)bh*NR*8;
    const _Float16* Vb = Vh + (size_t)bh*NR*8;

    for (int u = tid; u < NR; u += 256) {
        *(f16x8*)&KV[u*16]     = *(const f16x8*)&Kb[u*8];
        *(f16x8*)&KV[u*16 + 8] = *(const f16x8*)&Vb[u*8];
    }
    __syncthreads();

    const int wid = tid >> 6, lane = tid & 63;
    const int qu = lane >> 3, seg = lane & 7;
    const int nq = q0 + wid*8 + qu;
    const bool act = nq < NN;
    const int qm = act ? nq : NN-1;

    f16x8 qv = *(const f16x8*)(Qh + ((size_t)bh*NR + qm)*8);
    const f16x2* qh2 = (const f16x2*)&qv;
    const int ks = seg*KPS;

    const size_t mbase = ((size_t)qm*SEGS + seg)*2;
    const size_t mstep = (size_t)NN*SEGS*2;
    unsigned w00 = pmr[mbase],           w01 = pmr[mbase+1];
    unsigned w10 = pmr[mstep+mbase],     w11 = pmr[mstep+mbase+1];
    unsigned w20 = pmr[2*mstep+mbase],   w21 = pmr[2*mstep+mbase+1];

    float l0 = 0.f, l1 = 0.f, l2 = 0.f;
    f32x2 O0[4] = {{0,0},{0,0},{0,0},{0,0}};
    f32x2 O1[4] = {{0,0},{0,0},{0,0},{0,0}};
    f32x2 O2[4] = {{0,0},{0,0},{0,0},{0,0}};

    f16x8 kc = *(const f16x8*)&KV[ks*16];
    f16x8 vc = *(const f16x8*)&KV[ks*16 + 8];

    auto step = [&](int j, unsigned b0, unsigned b1, unsigned b2) {
        f16x8 kn = kc, vn = vc;
        if (j + 1 < KPS) {
            kn = *(const f16x8*)&KV[(ks + j + 1)*16];
            vn = *(const f16x8*)&KV[(ks + j + 1)*16 + 8];
        }
        const f16x2* k2 = (const f16x2*)&kc;
        float d = __builtin_amdgcn_fdot2(qh2[0], k2[0], -32.f, false);
        d = __builtin_amdgcn_fdot2(qh2[1], k2[1], d, false);
        d = __builtin_amdgcn_fdot2(qh2[2], k2[2], d, false);
        d = __builtin_amdgcn_fdot2(qh2[3], k2[3], d, false);
        float E = EXP2F(d);
        float E0 = b0 ? E : 0.f;
        float E1 = b1 ? E : 0.f;
        float E2 = b2 ? E : 0.f;
        l0 += E0; l1 += E1; l2 += E2;
        f32x2 e0 = {E0, E0}, e1 = {E1, E1}, e2 = {E2, E2};
        #pragma unroll
        for (int jj = 0; jj < 4; ++jj) {
            f32x2 vp = {(float)vc[2*jj], (float)vc[2*jj+1]};
            O0[jj] += e0 * vp;
            O1[jj] += e1 * vp;
            O2[jj] += e2 * vp;
        }
        kc = kn; vc = vn;
    };
    #pragma unroll
    for (int j = 0; j < 32; ++j)
        step(j, (w00 >> j) & 1u, (w10 >> j) & 1u, (w20 >> j) & 1u);
    #pragma unroll
    for (int j = 32; j < KPS; ++j)
        step(j, (w01 >> (j-32)) & 1u, (w11 >> (j-32)) & 1u, (w21 >> (j-32)) & 1u);

    #pragma unroll
    for (int off = 1; off <= 4; off <<= 1) {
        l0 += __shfl_xor(l0, off, 64);
        l1 += __shfl_xor(l1, off, 64);
        l2 += __shfl_xor(l2, off, 64);
        #pragma unroll
        for (int j = 0; j < 4; ++j) {
            #pragma unroll
            for (int c = 0; c < 2; ++c) {
                O0[j][c] += __shfl_xor(O0[j][c], off, 64);
                O1[j][c] += __shfl_xor(O1[j][c], off, 64);
                O2[j][c] += __shfl_xor(O2[j][c], off, 64);
            }
        }
    }

    if (act && seg == 0) {
        float i0 = 1.f/l0, i1 = 1.f/l1, i2 = 1.f/l2;
        _Float16* op = outs + (size_t)(bt*NN + nq)*192 + h*8;
        f16x8 o0, o1, o2;
        #pragma unroll
        for (int j = 0; j < 4; ++j) {
            o0[2*j] = (_Float16)(O0[j][0]*i0); o0[2*j+1] = (_Float16)(O0[j][1]*i0);
            o1[2*j] = (_Float16)(O1[j][0]*i1); o1[2*j+1] = (_Float16)(O1[j][1]*i1);
            o2[2*j] = (_Float16)(O2[j][0]*i2); o2[2*j+1] = (_Float16)(O2[j][1]*i2);
        }
        *(f16x8*)(op)       = o0;
        *(f16x8*)(op + 64)  = o1;
        *(f16x8*)(op + 128) = o2;
    }
}

// ---------------- spatial proj + residual + LN; a f16 [t][i][64], Wo rows d*3+i ----------------
__global__ __launch_bounds__(256)
void proj_res_ln_s_kernel(const _Float16* __restrict__ a, const float* __restrict__ xres,
                          const float* __restrict__ Wo, const float* __restrict__ gamma,
                          const float* __restrict__ beta, float* __restrict__ xout) {
    const int wid = threadIdx.x >> 6, lane = threadIdx.x & 63;
    const int token = blockIdx.x*4 + wid;
    if (token >= NT) return;
    const _Float16* ap = a + (size_t)token*192;
    const float a0 = (float)ap[lane];
    const float a1 = (float)ap[64 + lane];
    const float a2 = (float)ap[128 + lane];
    float y = 0.f;
    #pragma unroll
    for (int d = 0; d < 64; ++d) {
        y += __shfl(a0, d, 64) * Wo[(d*3+0)*64 + lane];
        y += __shfl(a1, d, 64) * Wo[(d*3+1)*64 + lane];
        y += __shfl(a2, d, 64) * Wo[(d*3+2)*64 + lane];
    }
    float r = xres[(size_t)token*64 + lane] + y;
    float mu = wave_reduce_sum(r) * (1.f/64.f);
    float diff = r - mu;
    float var = wave_reduce_sum(diff*diff) * (1.f/64.f);
    xout[(size_t)token*64 + lane] = diff * rsqrtf(var + EPS) * gamma[lane] + beta[lane];
}

// ---------------- fused tail (module 3): proj_s+LN, FFN0+LN, FFN1+LN -> out ----------------
__global__ __launch_bounds__(256)
void tail_fused(const _Float16* __restrict__ a, const float* __restrict__ xres,
                const float* __restrict__ Wo,
                const float* __restrict__ W1a, const float* __restrict__ W2a,
                const float* __restrict__ W1b, const float* __restrict__ W2b,
                const float* __restrict__ ln_g, const float* __restrict__ ln_b,
                float* __restrict__ out) {
    const int wid = threadIdx.x >> 6, lane = threadIdx.x & 63;
    const int token = blockIdx.x*4 + wid;
    if (token >= NT) return;
    const int c = lane & 15;

    const _Float16* ap = a + (size_t)token*192;
    const float a0 = (float)ap[lane];
    const float a1 = (float)ap[64 + lane];
    const float a2 = (float)ap[128 + lane];
    float y = 0.f;
    #pragma unroll
    for (int d = 0; d < 64; ++d) {
        y += __shfl(a0, d, 64) * Wo[(d*3+0)*64 + lane];
        y += __shfl(a1, d, 64) * Wo[(d*3+1)*64 + lane];
        y += __shfl(a2, d, 64) * Wo[(d*3+2)*64 + lane];
    }
    float r = xres[(size_t)token*64 + lane] + y;
    float mu = wave_reduce_sum(r) * (1.f/64.f);
    float diff = r - mu;
    float var = wave_reduce_sum(diff*diff) * (1.f/64.f);
    float x1 = diff * rsqrtf(var + EPS) * ln_g[lane] + ln_b[lane];

    float hs = 0.f;
    #pragma unroll
    for (int d = 0; d < 64; ++d) hs += __shfl(x1, d, 64) * W1a[d*16 + c];
    float hr = fmaxf(hs, 0.f);
    float y2 = 0.f;
    #pragma unroll
    for (int cc = 0; cc < 16; ++cc) y2 += __shfl(hr, cc, 64) * W2a[cc*64 + lane];
    r = x1 + y2;
    mu = wave_reduce_sum(r) * (1.f/64.f);
    diff = r - mu;
    var = wave_reduce_sum(diff*diff) * (1.f/64.f);
    float x2 = diff * rsqrtf(var + EPS) * ln_g[64 + lane] + ln_b[64 + lane];

    hs = 0.f;
    #pragma unroll
    for (int d = 0; d < 64; ++d) hs += __shfl(x2, d, 64) * W1b[d*16 + c];
    hr = fmaxf(hs, 0.f);
    y2 = 0.f;
    #pragma unroll
    for (int cc = 0; cc < 16; ++cc) y2 += __shfl(hr, cc, 64) * W2b[cc*64 + lane];
    r = x2 + y2;
    mu = wave_reduce_sum(r) * (1.f/64.f);
    diff = r - mu;
    var = wave_reduce_sum(diff*diff) * (1.f/64.f);
    out[(size_t)token*64 + lane] = diff * rsqrtf(var + EPS) * ln_g[128 + lane] + ln_b[128 + lane];
}

// ---------------- launcher ----------------
extern "C" void kernel_launch(void* const* d_in, const int* in_sizes, int n_in,
                              void* d_out, int out_size, void* d_ws, size_t ws_size,
                              hipStream_t stream) {
    const float* queries = (const float*)d_in[0];
    const float* keys    = (const float*)d_in[1];
    const float* values  = (const float*)d_in[2];
    const float* ste_q   = (const float*)d_in[3];
    const float* ste_k   = (const float*)d_in[4];
    const float* ste_v   = (const float*)d_in[5];
    const int*   tms     = (const int*)d_in[6];
    const float* mW1     = (const float*)d_in[7];
    const float* mb1     = (const float*)d_in[8];
    const float* mW2     = (const float*)d_in[9];
    const float* mb2     = (const float*)d_in[10];
    const float* Wo_t    = (const float*)d_in[11];
    const float* Wo_s    = (const float*)d_in[12];
    const float* ffn_W1  = (const float*)d_in[13];
    const float* ffn_W2  = (const float*)d_in[14];
    const float* ln_g    = (const float*)d_in[15];
    const float* ln_b    = (const float*)d_in[16];

    char* p = (char*)d_ws;
    auto carve = [&](size_t bytes) { char* r = p; p += (bytes + 255) & ~(size_t)255; return r; };
    float* xbuf = (float*)carve((size_t)NT64*4);
    float* qg   = (float*)carve((size_t)NT64*4);
    float* kg   = (float*)carve((size_t)NT64*4);
    float* vg   = (float*)carve((size_t)NT64*4);
    _Float16* as_ = (_Float16*)carve((size_t)NT*192*2);
    _Float16* Wt  = (_Float16*)carve((size_t)12*64*KTOT*2);
    _Float16* W1f = (_Float16*)carve((size_t)12*4096*2);
    unsigned* pmr = (unsigned*)carve((size_t)MM*NN*SEGS*2*4);
    _Float16* Qh  = (_Float16*)carve((size_t)BB*TT*HH*NR*8*2);
    _Float16* Kh  = (_Float16*)carve((size_t)BB*TT*HH*NR*8*2);
    _Float16* Vh  = (_Float16*)carve((size_t)BB*TT*HH*NR*8*2);

    const dim3 blk(256);
    const dim3 g_tok(NT/4);
    const dim3 g_sa(BB*TT*HH, 11);
    const dim3 g_gemm((NT + 63)/64, 3);

    // one-time prep (merged): 780 Wt blocks + 12 W1 blocks + 31 mask blocks
    prep_all<<<dim3(823), blk, 0, stream>>>(mW2, mb2, Wt, mW1, W1f, tms, pmr);

    // ---- module 0: temporal on (queries, keys, values), residual = queries ----
    meta_gemm_t<0><<<g_gemm, blk, 0, stream>>>(
        queries, keys, values, ste_q, ste_k, ste_v,
        W1f, mb1, Wt, (void*)qg, (void*)kg, (void*)vg);
    temporal_fused<<<g_tok, blk, 0, stream>>>(
        qg, kg, vg, queries, Wo_t, ln_g, ln_b, xbuf);

    // ---- module 1: spatial on x ----
    meta_gemm_t<1><<<g_gemm, blk, 0, stream>>>(
        xbuf, xbuf, xbuf, ste_q, ste_k, ste_v,
        W1f + (size_t)3*4096, mb1 + (size_t)3*64, Wt + (size_t)3*64*KTOT,
        (void*)Qh, (void*)Kh, (void*)Vh);
    spatial_attn13<<<g_sa, blk, 0, stream>>>(Qh, Kh, Vh, pmr, as_);
    proj_res_ln_s_kernel<<<g_tok, blk, 0, stream>>>(
        as_, xbuf, Wo_s, ln_g + 64, ln_b + 64, xbuf);

    // ---- module 2: temporal on x ----
    meta_gemm_t<0><<<g_gemm, blk, 0, stream>>>(
        xbuf, xbuf, xbuf, ste_q, ste_k, ste_v,
        W1f + (size_t)6*4096, mb1 + (size_t)6*64, Wt + (size_t)6*64*KTOT,
        (void*)qg, (void*)kg, (void*)vg);
    temporal_fused<<<g_tok, blk, 0, stream>>>(
        qg, kg, vg, xbuf, Wo_t + (size_t)64*64, ln_g + 128, ln_b + 128, xbuf);

    // ---- module 3: spatial on x + fused tail ----
    meta_gemm_t<1><<<g_gemm, blk, 0, stream>>>(
        xbuf, xbuf, xbuf, ste_q, ste_k, ste_v,
        W1f + (size_t)9*4096, mb1 + (size_t)9*64, Wt + (size_t)9*64*KTOT,
        (void*)Qh, (void*)Kh, (void*)Vh);
    spatial_attn13<<<g_sa, blk, 0, stream>>>(Qh, Kh, Vh, pmr, as_);
    tail_fused<<<g_tok, blk, 0, stream>>>(
        as_, xbuf, Wo_s + (size_t)192*64,
        ffn_W1, ffn_W2, ffn_W1 + (size_t)64*16, ffn_W2 + (size_t)16*64,
        ln_g + 192, ln_b + 192, (float*)d_out);
}

// Round 8
// 227.527 us; speedup vs baseline: 1.1074x; 1.1074x over previous
//
#include <hip/hip_runtime.h>
#include <math.h>

#define BB 2
#define TT 12
#define NN 325
#define DD 64
#define HH 8
#define MM 3
#define NT (BB*TT*NN)   // 7800
#define NT64 (NT*64)
#define EPS 1e-6f
#define KTOT 4160       // 64*64 + 64 (bias fold)
#define SEGS 8
#define KPS 41          // 8*41 = 328
#define NR 328

typedef _Float16 f16x8 __attribute__((ext_vector_type(8)));
typedef _Float16 f16x2 __attribute__((ext_vector_type(2)));
typedef float f32x4 __attribute__((ext_vector_type(4)));
typedef float f32x2 __attribute__((ext_vector_type(2)));

#if __has_builtin(__builtin_amdgcn_exp2f)
#define EXP2F(x) __builtin_amdgcn_exp2f(x)
#else
#define EXP2F(x) exp2f(x)
#endif

__device__ inline float wave_reduce_sum(float v) {
    #pragma unroll
    for (int o = 32; o > 0; o >>= 1) v += __shfl_xor(v, o, 64);
    return v;
}

__device__ inline float h2f(unsigned u) {
    unsigned short us = (unsigned short)u;
    _Float16 h;
    __builtin_memcpy(&h, &us, 2);
    return (float)h;
}

// ---------------- merged one-time prep:
//  blocks [0,780):   W2+b2 -> Wt[p][e][kk] f16 (K-major); p = bx/65, kk0 = (bx%65)*64
//  blocks [780,792): W1 transpose -> W1f
//  blocks [792,823): 8-seg mask words -> pmr
__global__ __launch_bounds__(256)
void prep_all(const float* __restrict__ mW2, const float* __restrict__ mb2,
              _Float16* __restrict__ Wt,
              const float* __restrict__ mW1, _Float16* __restrict__ W1f,
              const int* __restrict__ tms, unsigned* __restrict__ pmr) {
    const int bx = blockIdx.x;
    const int tid = threadIdx.x;
    if (bx < 780) {
        const int p = bx / 65;
        const int kk0 = (bx % 65) * 64;
        __shared__ float s[64][65];
        #pragma unroll
        for (int pass = 0; pass < 16; ++pass) {
            int idx = pass*256 + tid;
            int kl = idx >> 6, e = idx & 63;
            int kk = kk0 + kl;
            float v = (kk < 4096) ? mW2[(size_t)p*262144 + (size_t)kk*64 + e]
                                  : mb2[(size_t)p*4096 + (size_t)(kk-4096)*64 + e];
            s[kl][e] = v;
        }
        __syncthreads();
        #pragma unroll
        for (int pass = 0; pass < 16; ++pass) {
            int idx = pass*256 + tid;
            int e = idx >> 6, kl = idx & 63;
            Wt[(size_t)p*64*KTOT + (size_t)e*KTOT + kk0 + kl] = (_Float16)s[kl][e];
        }
        return;
    }
    if (bx < 792) {
        const int p = bx - 780;
        #pragma unroll
        for (int i = 0; i < 16; ++i) {
            int idx = i*256 + tid;
            int d = idx >> 6, e = idx & 63;
            W1f[(size_t)p*4096 + e*64 + d] = (_Float16)mW1[(size_t)p*4096 + d*64 + e];
        }
        return;
    }
    int idx = (bx - 792)*256 + tid;
    if (idx >= MM*NN*SEGS) return;
    int seg = idx & 7;
    int nq = (idx >> 3) % NN;
    int i = idx / (SEGS*NN);
    int ks = seg*KPS;
    int ke = (ks + KPS < NN) ? ks + KPS : NN;
    const int* row = tms + ((size_t)i*NN + nq)*NN;
    unsigned w0 = 0, w1 = 0;
    for (int k = ks; k < ke; ++k) {
        int b = k - ks;
        unsigned bit = (row[k] > 0) ? 1u : 0u;
        if (b < 32) w0 |= bit << b; else w1 |= bit << (b - 32);
    }
    pmr[(size_t)idx*2]     = w0;
    pmr[(size_t)idx*2 + 1] = w1;
}

// ---------------- meta GEMM v9 (round-5 anchor, best measured): 256 threads, 4 waves
// as 2M x 2N (wave = 32x32 tile). Each B ds_read_b128 feeds 2 MFMAs AND each
// A-product feeds 2 MFMAs. K-loop unrolled x4 with peeled tail (compile-time hv[]
// extracts). BK=128 dbuf, counted vmcnt(4), raw barriers. grid (122,3). ----------------
template<int MODE>
__global__ __launch_bounds__(256, 2)
void meta_gemm_t(const float* __restrict__ x0, const float* __restrict__ x1,
                 const float* __restrict__ x2,
                 const float* __restrict__ s0, const float* __restrict__ s1,
                 const float* __restrict__ s2,
                 const _Float16* __restrict__ W1f, const float* __restrict__ b1m,
                 const _Float16* __restrict__ Wtm,
                 void* __restrict__ o0, void* __restrict__ o1, void* __restrict__ o2) {
    const int br = blockIdx.y;
    const int t0 = blockIdx.x * 64;
    const float* xg = (br==0) ? x0 : (br==1) ? x1 : x2;
    const float* sg = (br==0) ? s0 : (br==1) ? s1 : s2;
    const _Float16* W1b = W1f + (size_t)br*4096;
    const float* b1g = b1m + (size_t)br*64;
    const _Float16* W = Wtm + (size_t)br*64*KTOT;
    void* outp = (br==0) ? o0 : (br==1) ? o1 : o2;

    __shared__ _Float16 sx[64*64];
    __shared__ _Float16 ss[64*64];
    __shared__ _Float16 shT[64*68];     // [t][c], stride 68
    __shared__ _Float16 bB[2][1024*8];  // 2 x 16KB, each = 2 K-steps of 64

    const int tid = threadIdx.x;
    // stage x/ste: 512 16B-units, 2 per thread
    #pragma unroll
    for (int i = 0; i < 2; ++i) {
        int idx = i*256 + tid;
        int row = idx >> 3, u = idx & 7;
        int t = t0 + row;
        int boff = row*128 + ((u*16) ^ ((row & 7) << 4));
        f16x8 xo, so;
        if (t < NT) {
            const float4* xp = (const float4*)(xg + (size_t)t*64 + u*8);
            float4 a = xp[0], b = xp[1];
            f16x8 xv = {(_Float16)a.x,(_Float16)a.y,(_Float16)a.z,(_Float16)a.w,
                        (_Float16)b.x,(_Float16)b.y,(_Float16)b.z,(_Float16)b.w};
            const float4* sp = (const float4*)(sg + (size_t)t*64 + u*8);
            float4 c = sp[0], d = sp[1];
            f16x8 sv = {(_Float16)c.x,(_Float16)c.y,(_Float16)c.z,(_Float16)c.w,
                        (_Float16)d.x,(_Float16)d.y,(_Float16)d.z,(_Float16)d.w};
            xo = xv; so = sv;
        } else {
            f16x8 z = {(_Float16)0.f,(_Float16)0.f,(_Float16)0.f,(_Float16)0.f,
                       (_Float16)0.f,(_Float16)0.f,(_Float16)0.f,(_Float16)0.f};
            xo = z; so = z;
        }
        *(f16x8*)((char*)sx + boff) = xo;
        *(f16x8*)((char*)ss + boff) = so;
    }
    __syncthreads();

    const int wid = tid >> 6, lane = tid & 63;
    const int col = lane & 15, g = lane >> 4;
    const int wm = wid & 1, wn = wid >> 1;          // 2M x 2N, wave tile 32x32
    const int trow0 = wm*32 + col;                  // wave's first M-tile row
    const int trow1 = trow0 + 16;                   // wave's second M-tile row
    const int rb0 = trow0*128, rb1 = trow1*128;
    const int sz = (trow0 & 7) << 4;                // same for trow1 (+16)

    // ---- h-phase: all 4 waves compute h for tokens wid*16..+15, store shT[t][c] ----
    {
        const int hrow = wid*16 + col;
        const int hrb = hrow*128;
        const int hsz = (hrow & 7) << 4;
        f32x4 ha[4] = {{0,0,0,0},{0,0,0,0},{0,0,0,0},{0,0,0,0}};
        #pragma unroll
        for (int ph = 0; ph < 2; ++ph) {
            int dd = ph*32 + g*8;
            f16x8 sv = *(f16x8*)((char*)ss + hrb + ((dd*2) ^ hsz));
            #pragma unroll
            for (int ni = 0; ni < 4; ++ni) {
                f16x8 bw = *(const f16x8*)(W1b + (size_t)(ni*16+col)*64 + dd);
                ha[ni] = __builtin_amdgcn_mfma_f32_16x16x32_f16(sv, bw, ha[ni], 0, 0, 0);
            }
        }
        #pragma unroll
        for (int ni = 0; ni < 4; ++ni) {
            float bv = b1g[ni*16+col];
            #pragma unroll
            for (int r = 0; r < 4; ++r)
                shT[(wid*16 + g*4 + r)*68 + ni*16 + col] = (_Float16)fmaxf(ha[ni][r] + bv, 0.f);
        }
    }

    // ---- hoisted K-invariant x fragments (two M-tiles per wave) ----
    f16x8 xv00 = *(f16x8*)((char*)sx + rb0 + (((g*8)*2) ^ sz));
    f16x8 xv01 = *(f16x8*)((char*)sx + rb0 + (((32 + g*8)*2) ^ sz));
    f16x8 xv10 = *(f16x8*)((char*)sx + rb1 + (((g*8)*2) ^ sz));
    f16x8 xv11 = *(f16x8*)((char*)sx + rb1 + (((32 + g*8)*2) ^ sz));

    auto STAGE2 = [&](int bi, int st2) {   // stage K-steps 2*st2, 2*st2+1 (128 K); 4 loads/thread
        const _Float16* base = W + (size_t)st2*128;
        #pragma unroll
        for (int j = 0; j < 4; ++j) {
            int p = j*256 + tid;                // 0..1023
            int t = p >> 9;
            int rest = p & 511;
            int e = rest >> 3, wu = rest & 7;
            const _Float16* src = base + (size_t)t*64 + (size_t)e*KTOT + ((wu ^ (e & 7)) << 3);
            __builtin_amdgcn_global_load_lds(
                (const __attribute__((address_space(1))) void*)src,
                (__attribute__((address_space(3))) void*)&bB[bi][p*8],
                16, 0, 0);
        }
    };
    auto STAGE1 = [&](int bi, int st) {    // stage single K-step st (64 K); 2 loads/thread
        const _Float16* base = W + (size_t)st*64;
        #pragma unroll
        for (int j = 0; j < 2; ++j) {
            int p = j*256 + tid;                // 0..511
            int e = p >> 3, wu = p & 7;
            const _Float16* src = base + (size_t)e*KTOT + ((wu ^ (e & 7)) << 3);
            __builtin_amdgcn_global_load_lds(
                (const __attribute__((address_space(1))) void*)src,
                (__attribute__((address_space(3))) void*)&bB[bi][p*8],
                16, 0, 0);
        }
    };

    STAGE2(0, 0);
    STAGE2(1, 1);
    asm volatile("s_waitcnt lgkmcnt(0)" ::: "memory");   // drain own LDS writes (shT/staging)
    __builtin_amdgcn_sched_barrier(0);

    f32x4 A[2][2] = {{{0,0,0,0},{0,0,0,0}},{{0,0,0,0},{0,0,0,0}}};  // A[mt][nj]
    f16x8 hv0 = {}, hv1 = {};

    // K-invariant B-read addressing: two 16-col e-slices per wave
    const int e0 = wn*32 + col;
    const int e1 = e0 + 16;
    const int u00 = e0*8 + (g ^ (e0 & 7));
    const int u01 = e0*8 + ((4 + g) ^ (e0 & 7));
    const int u10 = e1*8 + (g ^ (e1 & 7));
    const int u11 = e1*8 + ((4 + g) ^ (e1 & 7));

    auto COMPUTE = [&](const _Float16* Bb, int ci) {   // ci = st2&3 (compile-time at call sites)
        #pragma unroll
        for (int t = 0; t < 2; ++t) {
            _Float16 hc0 = hv0[ci*2 + t];
            _Float16 hc1 = hv1[ci*2 + t];
            const _Float16* Bs = Bb + t*512*8;
            f16x8 b00 = *(const f16x8*)((const char*)Bs + u00*16);
            f16x8 b01 = *(const f16x8*)((const char*)Bs + u01*16);
            f16x8 b10 = *(const f16x8*)((const char*)Bs + u10*16);
            f16x8 b11 = *(const f16x8*)((const char*)Bs + u11*16);
            f16x8 p00 = xv00 * hc0;
            f16x8 p10 = xv10 * hc1;
            A[0][0] = __builtin_amdgcn_mfma_f32_16x16x32_f16(p00, b00, A[0][0], 0, 0, 0);
            A[0][1] = __builtin_amdgcn_mfma_f32_16x16x32_f16(p00, b10, A[0][1], 0, 0, 0);
            A[1][0] = __builtin_amdgcn_mfma_f32_16x16x32_f16(p10, b00, A[1][0], 0, 0, 0);
            A[1][1] = __builtin_amdgcn_mfma_f32_16x16x32_f16(p10, b10, A[1][1], 0, 0, 0);
            f16x8 p01 = xv01 * hc0;
            f16x8 p11 = xv11 * hc1;
            A[0][0] = __builtin_amdgcn_mfma_f32_16x16x32_f16(p01, b01, A[0][0], 0, 0, 0);
            A[0][1] = __builtin_amdgcn_mfma_f32_16x16x32_f16(p01, b11, A[0][1], 0, 0, 0);
            A[1][0] = __builtin_amdgcn_mfma_f32_16x16x32_f16(p11, b01, A[1][0], 0, 0, 0);
            A[1][1] = __builtin_amdgcn_mfma_f32_16x16x32_f16(p11, b11, A[1][1], 0, 0, 0);
        }
    };

    // main loop: q covers st2 = 4q..4q+3, q = 0..6 (st2 0..27); all indices compile-time mod 4
    for (int q = 0; q < 7; ++q) {
        #pragma unroll
        for (int s = 0; s < 4; ++s) {
            asm volatile("s_waitcnt vmcnt(4)" ::: "memory");   // this buf's 4 loads done; next in flight
            __builtin_amdgcn_sched_barrier(0);
            __builtin_amdgcn_s_barrier();
            if (s == 0) {
                hv0 = *(f16x8*)&shT[trow0*68 + q*8];
                hv1 = *(f16x8*)&shT[trow1*68 + q*8];
            }
            COMPUTE(bB[s & 1], s);
            __builtin_amdgcn_s_barrier();
            STAGE2(s & 1, 4*q + s + 2);
        }
    }
    // peeled tail: st2 = 28..31
    asm volatile("s_waitcnt vmcnt(4)" ::: "memory");
    __builtin_amdgcn_sched_barrier(0);
    __builtin_amdgcn_s_barrier();
    hv0 = *(f16x8*)&shT[trow0*68 + 56];
    hv1 = *(f16x8*)&shT[trow1*68 + 56];
    COMPUTE(bB[0], 0);
    __builtin_amdgcn_s_barrier();
    STAGE2(0, 30);

    asm volatile("s_waitcnt vmcnt(4)" ::: "memory");
    __builtin_amdgcn_sched_barrier(0);
    __builtin_amdgcn_s_barrier();
    COMPUTE(bB[1], 1);
    __builtin_amdgcn_s_barrier();
    STAGE2(1, 31);

    asm volatile("s_waitcnt vmcnt(4)" ::: "memory");
    __builtin_amdgcn_sched_barrier(0);
    __builtin_amdgcn_s_barrier();
    COMPUTE(bB[0], 2);
    __builtin_amdgcn_s_barrier();

    asm volatile("s_waitcnt vmcnt(0)" ::: "memory");
    __builtin_amdgcn_sched_barrier(0);
    __builtin_amdgcn_s_barrier();
    COMPUTE(bB[1], 3);
    __builtin_amdgcn_s_barrier();

    STAGE1(0, 64);
    asm volatile("s_waitcnt vmcnt(0)" ::: "memory");
    __builtin_amdgcn_sched_barrier(0);
    __builtin_amdgcn_s_barrier();
    {
        // bias fold: A-operand = raw x (no h scale)
        const _Float16* Bs = bB[0];
        f16x8 b00 = *(const f16x8*)((const char*)Bs + u00*16);
        f16x8 b01 = *(const f16x8*)((const char*)Bs + u01*16);
        f16x8 b10 = *(const f16x8*)((const char*)Bs + u10*16);
        f16x8 b11 = *(const f16x8*)((const char*)Bs + u11*16);
        A[0][0] = __builtin_amdgcn_mfma_f32_16x16x32_f16(xv00, b00, A[0][0], 0, 0, 0);
        A[0][1] = __builtin_amdgcn_mfma_f32_16x16x32_f16(xv00, b10, A[0][1], 0, 0, 0);
        A[1][0] = __builtin_amdgcn_mfma_f32_16x16x32_f16(xv10, b00, A[1][0], 0, 0, 0);
        A[1][1] = __builtin_amdgcn_mfma_f32_16x16x32_f16(xv10, b10, A[1][1], 0, 0, 0);
        A[0][0] = __builtin_amdgcn_mfma_f32_16x16x32_f16(xv01, b01, A[0][0], 0, 0, 0);
        A[0][1] = __builtin_amdgcn_mfma_f32_16x16x32_f16(xv01, b11, A[0][1], 0, 0, 0);
        A[1][0] = __builtin_amdgcn_mfma_f32_16x16x32_f16(xv11, b01, A[1][0], 0, 0, 0);
        A[1][1] = __builtin_amdgcn_mfma_f32_16x16x32_f16(xv11, b11, A[1][1], 0, 0, 0);
    }

    if (MODE == 0) {
        float* op = (float*)outp;
        #pragma unroll
        for (int mt = 0; mt < 2; ++mt) {
            #pragma unroll
            for (int nj = 0; nj < 2; ++nj) {
                const int e = e0 + nj*16;
                #pragma unroll
                for (int r = 0; r < 4; ++r) {
                    int t = t0 + wm*32 + mt*16 + g*4 + r;
                    if (t < NT) op[(size_t)t*64 + e] = A[mt][nj][r];
                }
            }
        }
    } else {
        const float KSC = 0.35355339059327373f * 1.4426950408889634f;
        const float scl = (br == 1) ? KSC : 1.f;
        const int bt0 = t0 / NN;
        const int bound = (bt0 + 1)*NN;
        _Float16* op = (_Float16*)outp;
        #pragma unroll
        for (int mt = 0; mt < 2; ++mt) {
            #pragma unroll
            for (int nj = 0; nj < 2; ++nj) {
                const int e = e0 + nj*16;
                const int hh = e >> 3, dd = e & 7;
                #pragma unroll
                for (int r = 0; r < 4; ++r) {
                    int t = t0 + wm*32 + mt*16 + g*4 + r;
                    if (t < NT) {
                        int bt = (t >= bound) ? bt0 + 1 : bt0;
                        int n = t - bt*NN;
                        size_t pidx = ((size_t)(bt*8 + hh)*NR + n)*8 + dd;
                        op[pidx] = (_Float16)(A[mt][nj][r]*scl);
                    }
                }
            }
        }
    }
}

// ---------------- fused temporal attention + out-proj + residual + LN ----------------
__global__ __launch_bounds__(256)
void temporal_fused(const float* __restrict__ qg, const float* __restrict__ kg,
                    const float* __restrict__ vg, const float* __restrict__ xres,
                    const float* __restrict__ Wo, const float* __restrict__ gamma,
                    const float* __restrict__ beta, float* __restrict__ xout) {
    const int wid = threadIdx.x >> 6, lane = threadIdx.x & 63;
    const int token = blockIdx.x*4 + wid;
    if (token >= NT) return;
    const int n = token % NN;
    const int b = token / (NN*TT);
    const float scale = 0.35355339059327373f;
    const float qv = qg[(size_t)token*64 + lane] * scale;

    float s[TT], v[TT];
    #pragma unroll
    for (int kt = 0; kt < TT; ++kt) {
        size_t base = ((size_t)(b*TT + kt)*NN + n)*64 + lane;
        float kv = kg[base];
        v[kt] = vg[base];
        float d = qv * kv;
        d += __shfl_xor(d, 1, 64);
        d += __shfl_xor(d, 2, 64);
        d += __shfl_xor(d, 4, 64);
        s[kt] = d;
    }
    float m = s[0];
    #pragma unroll
    for (int kt = 1; kt < TT; ++kt) m = fmaxf(m, s[kt]);
    float l = 0.f, O = 0.f;
    #pragma unroll
    for (int kt = 0; kt < TT; ++kt) {
        float p = __expf(s[kt] - m);
        l += p;
        O += p * v[kt];
    }
    O /= l;
    float y = 0.f;
    #pragma unroll
    for (int d = 0; d < 64; ++d) y += __shfl(O, d, 64) * Wo[d*64 + lane];
    float r = xres[(size_t)token*64 + lane] + y;
    float mu = wave_reduce_sum(r) * (1.f/64.f);
    float diff = r - mu;
    float var = wave_reduce_sum(diff*diff) * (1.f/64.f);
    xout[(size_t)token*64 + lane] = diff * rsqrtf(var + EPS) * gamma[lane] + beta[lane];
}

// ---------------- spatial attention v13: interleaved KV LDS + register prefetch.
// 8-seg x 32q; grid (192, 11); lane = qu*8 + seg; 41 keys/seg. ----------------
__global__ __launch_bounds__(256)
void spatial_attn13(const _Float16* __restrict__ Qh, const _Float16* __restrict__ Kh,
                    const _Float16* __restrict__ Vh, const unsigned* __restrict__ pmr,
                    _Float16* __restrict__ outs) {
    const int bh = blockIdx.x;
    const int bt = bh >> 3, h = bh & 7;
    const int q0 = blockIdx.y * 32;
    __shared__ _Float16 KV[NR*16];    // [k][0:8)=K row, [k][8:16)=V row
    const int tid = threadIdx.x;
    const _Float16* Kb = Kh + (size_t)bh*NR*8;
    const _Float16* Vb = Vh + (size_t)bh*NR*8;

    for (int u = tid; u < NR; u += 256) {
        *(f16x8*)&KV[u*16]     = *(const f16x8*)&Kb[u*8];
        *(f16x8*)&KV[u*16 + 8] = *(const f16x8*)&Vb[u*8];
    }
    __syncthreads();

    const int wid = tid >> 6, lane = tid & 63;
    const int qu = lane >> 3, seg = lane & 7;
    const int nq = q0 + wid*8 + qu;
    const bool act = nq < NN;
    const int qm = act ? nq : NN-1;

    f16x8 qv = *(const f16x8*)(Qh + ((size_t)bh*NR + qm)*8);
    const f16x2* qh2 = (const f16x2*)&qv;
    const int ks = seg*KPS;

    const size_t mbase = ((size_t)qm*SEGS + seg)*2;
    const size_t mstep = (size_t)NN*SEGS*2;
    unsigned w00 = pmr[mbase],           w01 = pmr[mbase+1];
    unsigned w10 = pmr[mstep+mbase],     w11 = pmr[mstep+mbase+1];
    unsigned w20 = pmr[2*mstep+mbase],   w21 = pmr[2*mstep+mbase+1];

    float l0 = 0.f, l1 = 0.f, l2 = 0.f;
    f32x2 O0[4] = {{0,0},{0,0},{0,0},{0,0}};
    f32x2 O1[4] = {{0,0},{0,0},{0,0},{0,0}};
    f32x2 O2[4] = {{0,0},{0,0},{0,0},{0,0}};

    f16x8 kc = *(const f16x8*)&KV[ks*16];
    f16x8 vc = *(const f16x8*)&KV[ks*16 + 8];

    auto step = [&](int j, unsigned b0, unsigned b1, unsigned b2) {
        f16x8 kn = kc, vn = vc;
        if (j + 1 < KPS) {
            kn = *(const f16x8*)&KV[(ks + j + 1)*16];
            vn = *(const f16x8*)&KV[(ks + j + 1)*16 + 8];
        }
        const f16x2* k2 = (const f16x2*)&kc;
        float d = __builtin_amdgcn_fdot2(qh2[0], k2[0], -32.f, false);
        d = __builtin_amdgcn_fdot2(qh2[1], k2[1], d, false);
        d = __builtin_amdgcn_fdot2(qh2[2], k2[2], d, false);
        d = __builtin_amdgcn_fdot2(qh2[3], k2[3], d, false);
        float E = EXP2F(d);
        float E0 = b0 ? E : 0.f;
        float E1 = b1 ? E : 0.f;
        float E2 = b2 ? E : 0.f;
        l0 += E0; l1 += E1; l2 += E2;
        f32x2 e0 = {E0, E0}, e1 = {E1, E1}, e2 = {E2, E2};
        #pragma unroll
        for (int jj = 0; jj < 4; ++jj) {
            f32x2 vp = {(float)vc[2*jj], (float)vc[2*jj+1]};
            O0[jj] += e0 * vp;
            O1[jj] += e1 * vp;
            O2[jj] += e2 * vp;
        }
        kc = kn; vc = vn;
    };
    #pragma unroll
    for (int j = 0; j < 32; ++j)
        step(j, (w00 >> j) & 1u, (w10 >> j) & 1u, (w20 >> j) & 1u);
    #pragma unroll
    for (int j = 32; j < KPS; ++j)
        step(j, (w01 >> (j-32)) & 1u, (w11 >> (j-32)) & 1u, (w21 >> (j-32)) & 1u);

    #pragma unroll
    for (int off = 1; off <= 4; off <<= 1) {
        l0 += __shfl_xor(l0, off, 64);
        l1 += __shfl_xor(l1, off, 64);
        l2 += __shfl_xor(l2, off, 64);
        #pragma unroll
        for (int j = 0; j < 4; ++j) {
            #pragma unroll
            for (int c = 0; c < 2; ++c) {
                O0[j][c] += __shfl_xor(O0[j][c], off, 64);
                O1[j][c] += __shfl_xor(O1[j][c], off, 64);
                O2[j][c] += __shfl_xor(O2[j][c], off, 64);
            }
        }
    }

    if (act && seg == 0) {
        float i0 = 1.f/l0, i1 = 1.f/l1, i2 = 1.f/l2;
        _Float16* op = outs + (size_t)(bt*NN + nq)*192 + h*8;
        f16x8 o0, o1, o2;
        #pragma unroll
        for (int j = 0; j < 4; ++j) {
            o0[2*j] = (_Float16)(O0[j][0]*i0); o0[2*j+1] = (_Float16)(O0[j][1]*i0);
            o1[2*j] = (_Float16)(O1[j][0]*i1); o1[2*j+1] = (_Float16)(O1[j][1]*i1);
            o2[2*j] = (_Float16)(O2[j][0]*i2); o2[2*j+1] = (_Float16)(O2[j][1]*i2);
        }
        *(f16x8*)(op)       = o0;
        *(f16x8*)(op + 64)  = o1;
        *(f16x8*)(op + 128) = o2;
    }
}

// ---------------- spatial proj + residual + LN; a f16 [t][i][64], Wo rows d*3+i.
// v2: a-row read via wave-uniform SCALAR loads (no bpermute); 3 parallel acc chains. ----------------
__global__ __launch_bounds__(256)
void proj_res_ln_s_kernel(const _Float16* __restrict__ a, const float* __restrict__ xres,
                          const float* __restrict__ Wo, const float* __restrict__ gamma,
                          const float* __restrict__ beta, float* __restrict__ xout) {
    const int wid = threadIdx.x >> 6, lane = threadIdx.x & 63;
    const int token = blockIdx.x*4 + wid;
    if (token >= NT) return;
    const int tu = __builtin_amdgcn_readfirstlane(token);
    const unsigned* aw = (const unsigned*)(a + (size_t)tu*192);  // 96 dwords: 3 rows x 32
    float y0 = 0.f, y1 = 0.f, y2 = 0.f;
    #pragma unroll
    for (int dd = 0; dd < 32; ++dd) {
        unsigned w0 = aw[dd], w1 = aw[32+dd], w2 = aw[64+dd];   // scalar (uniform) loads
        const float* W0 = Wo + (size_t)(6*dd)*64 + lane;        // rows 6dd..6dd+5
        y0 = fmaf(h2f(w0 & 0xffffu), W0[0],   y0);
        y1 = fmaf(h2f(w1 & 0xffffu), W0[64],  y1);
        y2 = fmaf(h2f(w2 & 0xffffu), W0[128], y2);
        y0 = fmaf(h2f(w0 >> 16),     W0[192], y0);
        y1 = fmaf(h2f(w1 >> 16),     W0[256], y1);
        y2 = fmaf(h2f(w2 >> 16),     W0[320], y2);
    }
    float y = y0 + y1 + y2;
    float r = xres[(size_t)token*64 + lane] + y;
    float mu = wave_reduce_sum(r) * (1.f/64.f);
    float diff = r - mu;
    float var = wave_reduce_sum(diff*diff) * (1.f/64.f);
    xout[(size_t)token*64 + lane] = diff * rsqrtf(var + EPS) * gamma[lane] + beta[lane];
}

// ---------------- fused tail (module 3): proj_s+LN, FFN0+LN, FFN1+LN -> out.
// v2: proj a-row via scalar loads (no bpermute), 3 parallel acc chains. ----------------
__global__ __launch_bounds__(256)
void tail_fused(const _Float16* __restrict__ a, const float* __restrict__ xres,
                const float* __restrict__ Wo,
                const float* __restrict__ W1a, const float* __restrict__ W2a,
                const float* __restrict__ W1b, const float* __restrict__ W2b,
                const float* __restrict__ ln_g, const float* __restrict__ ln_b,
                float* __restrict__ out) {
    const int wid = threadIdx.x >> 6, lane = threadIdx.x & 63;
    const int token = blockIdx.x*4 + wid;
    if (token >= NT) return;
    const int c = lane & 15;

    const int tu = __builtin_amdgcn_readfirstlane(token);
    const unsigned* aw = (const unsigned*)(a + (size_t)tu*192);  // 96 dwords: 3 rows x 32
    float y0 = 0.f, y1 = 0.f, y2 = 0.f;
    #pragma unroll
    for (int dd = 0; dd < 32; ++dd) {
        unsigned w0 = aw[dd], w1 = aw[32+dd], w2 = aw[64+dd];   // scalar (uniform) loads
        const float* W0 = Wo + (size_t)(6*dd)*64 + lane;        // rows 6dd..6dd+5
        y0 = fmaf(h2f(w0 & 0xffffu), W0[0],   y0);
        y1 = fmaf(h2f(w1 & 0xffffu), W0[64],  y1);
        y2 = fmaf(h2f(w2 & 0xffffu), W0[128], y2);
        y0 = fmaf(h2f(w0 >> 16),     W0[192], y0);
        y1 = fmaf(h2f(w1 >> 16),     W0[256], y1);
        y2 = fmaf(h2f(w2 >> 16),     W0[320], y2);
    }
    float y = y0 + y1 + y2;
    float r = xres[(size_t)token*64 + lane] + y;
    float mu = wave_reduce_sum(r) * (1.f/64.f);
    float diff = r - mu;
    float var = wave_reduce_sum(diff*diff) * (1.f/64.f);
    float x1 = diff * rsqrtf(var + EPS) * ln_g[lane] + ln_b[lane];

    float hs = 0.f;
    #pragma unroll
    for (int d = 0; d < 64; ++d) hs += __shfl(x1, d, 64) * W1a[d*16 + c];
    float hr = fmaxf(hs, 0.f);
    float y2b = 0.f;
    #pragma unroll
    for (int cc = 0; cc < 16; ++cc) y2b += __shfl(hr, cc, 64) * W2a[cc*64 + lane];
    r = x1 + y2b;
    mu = wave_reduce_sum(r) * (1.f/64.f);
    diff = r - mu;
    var = wave_reduce_sum(diff*diff) * (1.f/64.f);
    float x2 = diff * rsqrtf(var + EPS) * ln_g[64 + lane] + ln_b[64 + lane];

    hs = 0.f;
    #pragma unroll
    for (int d = 0; d < 64; ++d) hs += __shfl(x2, d, 64) * W1b[d*16 + c];
    hr = fmaxf(hs, 0.f);
    y2b = 0.f;
    #pragma unroll
    for (int cc = 0; cc < 16; ++cc) y2b += __shfl(hr, cc, 64) * W2b[cc*64 + lane];
    r = x2 + y2b;
    mu = wave_reduce_sum(r) * (1.f/64.f);
    diff = r - mu;
    var = wave_reduce_sum(diff*diff) * (1.f/64.f);
    out[(size_t)token*64 + lane] = diff * rsqrtf(var + EPS) * ln_g[128 + lane] + ln_b[128 + lane];
}

// ---------------- launcher ----------------
extern "C" void kernel_launch(void* const* d_in, const int* in_sizes, int n_in,
                              void* d_out, int out_size, void* d_ws, size_t ws_size,
                              hipStream_t stream) {
    const float* queries = (const float*)d_in[0];
    const float* keys    = (const float*)d_in[1];
    const float* values  = (const float*)d_in[2];
    const float* ste_q   = (const float*)d_in[3];
    const float* ste_k   = (const float*)d_in[4];
    const float* ste_v   = (const float*)d_in[5];
    const int*   tms     = (const int*)d_in[6];
    const float* mW1     = (const float*)d_in[7];
    const float* mb1     = (const float*)d_in[8];
    const float* mW2     = (const float*)d_in[9];
    const float* mb2     = (const float*)d_in[10];
    const float* Wo_t    = (const float*)d_in[11];
    const float* Wo_s    = (const float*)d_in[12];
    const float* ffn_W1  = (const float*)d_in[13];
    const float* ffn_W2  = (const float*)d_in[14];
    const float* ln_g    = (const float*)d_in[15];
    const float* ln_b    = (const float*)d_in[16];

    char* p = (char*)d_ws;
    auto carve = [&](size_t bytes) { char* r = p; p += (bytes + 255) & ~(size_t)255; return r; };
    float* xbuf = (float*)carve((size_t)NT64*4);
    float* qg   = (float*)carve((size_t)NT64*4);
    float* kg   = (float*)carve((size_t)NT64*4);
    float* vg   = (float*)carve((size_t)NT64*4);
    _Float16* as_ = (_Float16*)carve((size_t)NT*192*2);
    _Float16* Wt  = (_Float16*)carve((size_t)12*64*KTOT*2);
    _Float16* W1f = (_Float16*)carve((size_t)12*4096*2);
    unsigned* pmr = (unsigned*)carve((size_t)MM*NN*SEGS*2*4);
    _Float16* Qh  = (_Float16*)carve((size_t)BB*TT*HH*NR*8*2);
    _Float16* Kh  = (_Float16*)carve((size_t)BB*TT*HH*NR*8*2);
    _Float16* Vh  = (_Float16*)carve((size_t)BB*TT*HH*NR*8*2);

    const dim3 blk(256);
    const dim3 g_tok(NT/4);
    const dim3 g_sa(BB*TT*HH, 11);
    const dim3 g_gemm((NT + 63)/64, 3);

    // one-time prep (merged): 780 Wt blocks + 12 W1 blocks + 31 mask blocks
    prep_all<<<dim3(823), blk, 0, stream>>>(mW2, mb2, Wt, mW1, W1f, tms, pmr);

    // ---- module 0: temporal on (queries, keys, values), residual = queries ----
    meta_gemm_t<0><<<g_gemm, blk, 0, stream>>>(
        queries, keys, values, ste_q, ste_k, ste_v,
        W1f, mb1, Wt, (void*)qg, (void*)kg, (void*)vg);
    temporal_fused<<<g_tok, blk, 0, stream>>>(
        qg, kg, vg, queries, Wo_t, ln_g, ln_b, xbuf);

    // ---- module 1: spatial on x ----
    meta_gemm_t<1><<<g_gemm, blk, 0, stream>>>(
        xbuf, xbuf, xbuf, ste_q, ste_k, ste_v,
        W1f + (size_t)3*4096, mb1 + (size_t)3*64, Wt + (size_t)3*64*KTOT,
        (void*)Qh, (void*)Kh, (void*)Vh);
    spatial_attn13<<<g_sa, blk, 0, stream>>>(Qh, Kh, Vh, pmr, as_);
    proj_res_ln_s_kernel<<<g_tok, blk, 0, stream>>>(
        as_, xbuf, Wo_s, ln_g + 64, ln_b + 64, xbuf);

    // ---- module 2: temporal on x ----
    meta_gemm_t<0><<<g_gemm, blk, 0, stream>>>(
        xbuf, xbuf, xbuf, ste_q, ste_k, ste_v,
        W1f + (size_t)6*4096, mb1 + (size_t)6*64, Wt + (size_t)6*64*KTOT,
        (void*)qg, (void*)kg, (void*)vg);
    temporal_fused<<<g_tok, blk, 0, stream>>>(
        qg, kg, vg, xbuf, Wo_t + (size_t)64*64, ln_g + 128, ln_b + 128, xbuf);

    // ---- module 3: spatial on x + fused tail ----
    meta_gemm_t<1><<<g_gemm, blk, 0, stream>>>(
        xbuf, xbuf, xbuf, ste_q, ste_k, ste_v,
        W1f + (size_t)9*4096, mb1 + (size_t)9*64, Wt + (size_t)9*64*KTOT,
        (void*)Qh, (void*)Kh, (void*)Vh);
    spatial_attn13<<<g_sa, blk, 0, stream>>>(Qh, Kh, Vh, pmr, as_);
    tail_fused<<<g_tok, blk, 0, stream>>>(
        as_, xbuf, Wo_s + (size_t)192*64,
        ffn_W1, ffn_W2, ffn_W1 + (size_t)64*16, ffn_W2 + (size_t)16*64,
        ln_g + 192, ln_b + 192, (float*)d_out);
}

// Round 9
// 226.522 us; speedup vs baseline: 1.1123x; 1.0044x over previous
//
#include <hip/hip_runtime.h>
#include <math.h>

#define BB 2
#define TT 12
#define NN 325
#define DD 64
#define HH 8
#define MM 3
#define NT (BB*TT*NN)   // 7800
#define NT64 (NT*64)
#define EPS 1e-6f
#define KTOT 4160       // 64*64 + 64 (bias fold)
#define SEGS 8
#define KPS 41          // 8*41 = 328
#define NR 328

typedef _Float16 f16x8 __attribute__((ext_vector_type(8)));
typedef _Float16 f16x2 __attribute__((ext_vector_type(2)));
typedef float f32x4 __attribute__((ext_vector_type(4)));
typedef float f32x2 __attribute__((ext_vector_type(2)));

#if __has_builtin(__builtin_amdgcn_exp2f)
#define EXP2F(x) __builtin_amdgcn_exp2f(x)
#else
#define EXP2F(x) exp2f(x)
#endif

__device__ inline float wave_reduce_sum(float v) {
    #pragma unroll
    for (int o = 32; o > 0; o >>= 1) v += __shfl_xor(v, o, 64);
    return v;
}

__device__ inline float h2f(unsigned u) {
    unsigned short us = (unsigned short)u;
    _Float16 h;
    __builtin_memcpy(&h, &us, 2);
    return (float)h;
}

// ---------------- merged one-time prep:
//  blocks [0,780):   W2+b2 -> Wt[p][e][kk] f16 (K-major); p = bx/65, kk0 = (bx%65)*64
//  blocks [780,792): W1 transpose -> W1f
//  blocks [792,823): 8-seg mask words -> pmr
__global__ __launch_bounds__(256)
void prep_all(const float* __restrict__ mW2, const float* __restrict__ mb2,
              _Float16* __restrict__ Wt,
              const float* __restrict__ mW1, _Float16* __restrict__ W1f,
              const int* __restrict__ tms, unsigned* __restrict__ pmr) {
    const int bx = blockIdx.x;
    const int tid = threadIdx.x;
    if (bx < 780) {
        const int p = bx / 65;
        const int kk0 = (bx % 65) * 64;
        __shared__ float s[64][65];
        #pragma unroll
        for (int pass = 0; pass < 16; ++pass) {
            int idx = pass*256 + tid;
            int kl = idx >> 6, e = idx & 63;
            int kk = kk0 + kl;
            float v = (kk < 4096) ? mW2[(size_t)p*262144 + (size_t)kk*64 + e]
                                  : mb2[(size_t)p*4096 + (size_t)(kk-4096)*64 + e];
            s[kl][e] = v;
        }
        __syncthreads();
        #pragma unroll
        for (int pass = 0; pass < 16; ++pass) {
            int idx = pass*256 + tid;
            int e = idx >> 6, kl = idx & 63;
            Wt[(size_t)p*64*KTOT + (size_t)e*KTOT + kk0 + kl] = (_Float16)s[kl][e];
        }
        return;
    }
    if (bx < 792) {
        const int p = bx - 780;
        #pragma unroll
        for (int i = 0; i < 16; ++i) {
            int idx = i*256 + tid;
            int d = idx >> 6, e = idx & 63;
            W1f[(size_t)p*4096 + e*64 + d] = (_Float16)mW1[(size_t)p*4096 + d*64 + e];
        }
        return;
    }
    int idx = (bx - 792)*256 + tid;
    if (idx >= MM*NN*SEGS) return;
    int seg = idx & 7;
    int nq = (idx >> 3) % NN;
    int i = idx / (SEGS*NN);
    int ks = seg*KPS;
    int ke = (ks + KPS < NN) ? ks + KPS : NN;
    const int* row = tms + ((size_t)i*NN + nq)*NN;
    unsigned w0 = 0, w1 = 0;
    for (int k = ks; k < ke; ++k) {
        int b = k - ks;
        unsigned bit = (row[k] > 0) ? 1u : 0u;
        if (b < 32) w0 |= bit << b; else w1 |= bit << (b - 32);
    }
    pmr[(size_t)idx*2]     = w0;
    pmr[(size_t)idx*2 + 1] = w1;
}

// ---------------- meta GEMM v9 (round-5 anchor, best measured): 256 threads, 4 waves
// as 2M x 2N (wave = 32x32 tile). Each B ds_read_b128 feeds 2 MFMAs AND each
// A-product feeds 2 MFMAs. K-loop unrolled x4 with peeled tail (compile-time hv[]
// extracts). BK=128 dbuf, counted vmcnt(4), raw barriers. grid (122,3). ----------------
template<int MODE>
__global__ __launch_bounds__(256, 2)
void meta_gemm_t(const float* __restrict__ x0, const float* __restrict__ x1,
                 const float* __restrict__ x2,
                 const float* __restrict__ s0, const float* __restrict__ s1,
                 const float* __restrict__ s2,
                 const _Float16* __restrict__ W1f, const float* __restrict__ b1m,
                 const _Float16* __restrict__ Wtm,
                 void* __restrict__ o0, void* __restrict__ o1, void* __restrict__ o2) {
    const int br = blockIdx.y;
    const int t0 = blockIdx.x * 64;
    const float* xg = (br==0) ? x0 : (br==1) ? x1 : x2;
    const float* sg = (br==0) ? s0 : (br==1) ? s1 : s2;
    const _Float16* W1b = W1f + (size_t)br*4096;
    const float* b1g = b1m + (size_t)br*64;
    const _Float16* W = Wtm + (size_t)br*64*KTOT;
    void* outp = (br==0) ? o0 : (br==1) ? o1 : o2;

    __shared__ _Float16 sx[64*64];
    __shared__ _Float16 ss[64*64];
    __shared__ _Float16 shT[64*68];     // [t][c], stride 68
    __shared__ _Float16 bB[2][1024*8];  // 2 x 16KB, each = 2 K-steps of 64

    const int tid = threadIdx.x;
    // stage x/ste: 512 16B-units, 2 per thread
    #pragma unroll
    for (int i = 0; i < 2; ++i) {
        int idx = i*256 + tid;
        int row = idx >> 3, u = idx & 7;
        int t = t0 + row;
        int boff = row*128 + ((u*16) ^ ((row & 7) << 4));
        f16x8 xo, so;
        if (t < NT) {
            const float4* xp = (const float4*)(xg + (size_t)t*64 + u*8);
            float4 a = xp[0], b = xp[1];
            f16x8 xv = {(_Float16)a.x,(_Float16)a.y,(_Float16)a.z,(_Float16)a.w,
                        (_Float16)b.x,(_Float16)b.y,(_Float16)b.z,(_Float16)b.w};
            const float4* sp = (const float4*)(sg + (size_t)t*64 + u*8);
            float4 c = sp[0], d = sp[1];
            f16x8 sv = {(_Float16)c.x,(_Float16)c.y,(_Float16)c.z,(_Float16)c.w,
                        (_Float16)d.x,(_Float16)d.y,(_Float16)d.z,(_Float16)d.w};
            xo = xv; so = sv;
        } else {
            f16x8 z = {(_Float16)0.f,(_Float16)0.f,(_Float16)0.f,(_Float16)0.f,
                       (_Float16)0.f,(_Float16)0.f,(_Float16)0.f,(_Float16)0.f};
            xo = z; so = z;
        }
        *(f16x8*)((char*)sx + boff) = xo;
        *(f16x8*)((char*)ss + boff) = so;
    }
    __syncthreads();

    const int wid = tid >> 6, lane = tid & 63;
    const int col = lane & 15, g = lane >> 4;
    const int wm = wid & 1, wn = wid >> 1;          // 2M x 2N, wave tile 32x32
    const int trow0 = wm*32 + col;                  // wave's first M-tile row
    const int trow1 = trow0 + 16;                   // wave's second M-tile row
    const int rb0 = trow0*128, rb1 = trow1*128;
    const int sz = (trow0 & 7) << 4;                // same for trow1 (+16)

    // ---- h-phase: all 4 waves compute h for tokens wid*16..+15, store shT[t][c] ----
    {
        const int hrow = wid*16 + col;
        const int hrb = hrow*128;
        const int hsz = (hrow & 7) << 4;
        f32x4 ha[4] = {{0,0,0,0},{0,0,0,0},{0,0,0,0},{0,0,0,0}};
        #pragma unroll
        for (int ph = 0; ph < 2; ++ph) {
            int dd = ph*32 + g*8;
            f16x8 sv = *(f16x8*)((char*)ss + hrb + ((dd*2) ^ hsz));
            #pragma unroll
            for (int ni = 0; ni < 4; ++ni) {
                f16x8 bw = *(const f16x8*)(W1b + (size_t)(ni*16+col)*64 + dd);
                ha[ni] = __builtin_amdgcn_mfma_f32_16x16x32_f16(sv, bw, ha[ni], 0, 0, 0);
            }
        }
        #pragma unroll
        for (int ni = 0; ni < 4; ++ni) {
            float bv = b1g[ni*16+col];
            #pragma unroll
            for (int r = 0; r < 4; ++r)
                shT[(wid*16 + g*4 + r)*68 + ni*16 + col] = (_Float16)fmaxf(ha[ni][r] + bv, 0.f);
        }
    }

    // ---- hoisted K-invariant x fragments (two M-tiles per wave) ----
    f16x8 xv00 = *(f16x8*)((char*)sx + rb0 + (((g*8)*2) ^ sz));
    f16x8 xv01 = *(f16x8*)((char*)sx + rb0 + (((32 + g*8)*2) ^ sz));
    f16x8 xv10 = *(f16x8*)((char*)sx + rb1 + (((g*8)*2) ^ sz));
    f16x8 xv11 = *(f16x8*)((char*)sx + rb1 + (((32 + g*8)*2) ^ sz));

    auto STAGE2 = [&](int bi, int st2) {   // stage K-steps 2*st2, 2*st2+1 (128 K); 4 loads/thread
        const _Float16* base = W + (size_t)st2*128;
        #pragma unroll
        for (int j = 0; j < 4; ++j) {
            int p = j*256 + tid;                // 0..1023
            int t = p >> 9;
            int rest = p & 511;
            int e = rest >> 3, wu = rest & 7;
            const _Float16* src = base + (size_t)t*64 + (size_t)e*KTOT + ((wu ^ (e & 7)) << 3);
            __builtin_amdgcn_global_load_lds(
                (const __attribute__((address_space(1))) void*)src,
                (__attribute__((address_space(3))) void*)&bB[bi][p*8],
                16, 0, 0);
        }
    };
    auto STAGE1 = [&](int bi, int st) {    // stage single K-step st (64 K); 2 loads/thread
        const _Float16* base = W + (size_t)st*64;
        #pragma unroll
        for (int j = 0; j < 2; ++j) {
            int p = j*256 + tid;                // 0..511
            int e = p >> 3, wu = p & 7;
            const _Float16* src = base + (size_t)e*KTOT + ((wu ^ (e & 7)) << 3);
            __builtin_amdgcn_global_load_lds(
                (const __attribute__((address_space(1))) void*)src,
                (__attribute__((address_space(3))) void*)&bB[bi][p*8],
                16, 0, 0);
        }
    };

    STAGE2(0, 0);
    STAGE2(1, 1);
    asm volatile("s_waitcnt lgkmcnt(0)" ::: "memory");   // drain own LDS writes (shT/staging)
    __builtin_amdgcn_sched_barrier(0);

    f32x4 A[2][2] = {{{0,0,0,0},{0,0,0,0}},{{0,0,0,0},{0,0,0,0}}};  // A[mt][nj]
    f16x8 hv0 = {}, hv1 = {};

    // K-invariant B-read addressing: two 16-col e-slices per wave
    const int e0 = wn*32 + col;
    const int e1 = e0 + 16;
    const int u00 = e0*8 + (g ^ (e0 & 7));
    const int u01 = e0*8 + ((4 + g) ^ (e0 & 7));
    const int u10 = e1*8 + (g ^ (e1 & 7));
    const int u11 = e1*8 + ((4 + g) ^ (e1 & 7));

    auto COMPUTE = [&](const _Float16* Bb, int ci) {   // ci = st2&3 (compile-time at call sites)
        #pragma unroll
        for (int t = 0; t < 2; ++t) {
            _Float16 hc0 = hv0[ci*2 + t];
            _Float16 hc1 = hv1[ci*2 + t];
            const _Float16* Bs = Bb + t*512*8;
            f16x8 b00 = *(const f16x8*)((const char*)Bs + u00*16);
            f16x8 b01 = *(const f16x8*)((const char*)Bs + u01*16);
            f16x8 b10 = *(const f16x8*)((const char*)Bs + u10*16);
            f16x8 b11 = *(const f16x8*)((const char*)Bs + u11*16);
            f16x8 p00 = xv00 * hc0;
            f16x8 p10 = xv10 * hc1;
            A[0][0] = __builtin_amdgcn_mfma_f32_16x16x32_f16(p00, b00, A[0][0], 0, 0, 0);
            A[0][1] = __builtin_amdgcn_mfma_f32_16x16x32_f16(p00, b10, A[0][1], 0, 0, 0);
            A[1][0] = __builtin_amdgcn_mfma_f32_16x16x32_f16(p10, b00, A[1][0], 0, 0, 0);
            A[1][1] = __builtin_amdgcn_mfma_f32_16x16x32_f16(p10, b10, A[1][1], 0, 0, 0);
            f16x8 p01 = xv01 * hc0;
            f16x8 p11 = xv11 * hc1;
            A[0][0] = __builtin_amdgcn_mfma_f32_16x16x32_f16(p01, b01, A[0][0], 0, 0, 0);
            A[0][1] = __builtin_amdgcn_mfma_f32_16x16x32_f16(p01, b11, A[0][1], 0, 0, 0);
            A[1][0] = __builtin_amdgcn_mfma_f32_16x16x32_f16(p11, b01, A[1][0], 0, 0, 0);
            A[1][1] = __builtin_amdgcn_mfma_f32_16x16x32_f16(p11, b11, A[1][1], 0, 0, 0);
        }
    };

    // main loop: q covers st2 = 4q..4q+3, q = 0..6 (st2 0..27); all indices compile-time mod 4
    for (int q = 0; q < 7; ++q) {
        #pragma unroll
        for (int s = 0; s < 4; ++s) {
            asm volatile("s_waitcnt vmcnt(4)" ::: "memory");   // this buf's 4 loads done; next in flight
            __builtin_amdgcn_sched_barrier(0);
            __builtin_amdgcn_s_barrier();
            if (s == 0) {
                hv0 = *(f16x8*)&shT[trow0*68 + q*8];
                hv1 = *(f16x8*)&shT[trow1*68 + q*8];
            }
            COMPUTE(bB[s & 1], s);
            __builtin_amdgcn_s_barrier();
            STAGE2(s & 1, 4*q + s + 2);
        }
    }
    // peeled tail: st2 = 28..31
    asm volatile("s_waitcnt vmcnt(4)" ::: "memory");
    __builtin_amdgcn_sched_barrier(0);
    __builtin_amdgcn_s_barrier();
    hv0 = *(f16x8*)&shT[trow0*68 + 56];
    hv1 = *(f16x8*)&shT[trow1*68 + 56];
    COMPUTE(bB[0], 0);
    __builtin_amdgcn_s_barrier();
    STAGE2(0, 30);

    asm volatile("s_waitcnt vmcnt(4)" ::: "memory");
    __builtin_amdgcn_sched_barrier(0);
    __builtin_amdgcn_s_barrier();
    COMPUTE(bB[1], 1);
    __builtin_amdgcn_s_barrier();
    STAGE2(1, 31);

    asm volatile("s_waitcnt vmcnt(4)" ::: "memory");
    __builtin_amdgcn_sched_barrier(0);
    __builtin_amdgcn_s_barrier();
    COMPUTE(bB[0], 2);
    __builtin_amdgcn_s_barrier();

    asm volatile("s_waitcnt vmcnt(0)" ::: "memory");
    __builtin_amdgcn_sched_barrier(0);
    __builtin_amdgcn_s_barrier();
    COMPUTE(bB[1], 3);
    __builtin_amdgcn_s_barrier();

    STAGE1(0, 64);
    asm volatile("s_waitcnt vmcnt(0)" ::: "memory");
    __builtin_amdgcn_sched_barrier(0);
    __builtin_amdgcn_s_barrier();
    {
        // bias fold: A-operand = raw x (no h scale)
        const _Float16* Bs = bB[0];
        f16x8 b00 = *(const f16x8*)((const char*)Bs + u00*16);
        f16x8 b01 = *(const f16x8*)((const char*)Bs + u01*16);
        f16x8 b10 = *(const f16x8*)((const char*)Bs + u10*16);
        f16x8 b11 = *(const f16x8*)((const char*)Bs + u11*16);
        A[0][0] = __builtin_amdgcn_mfma_f32_16x16x32_f16(xv00, b00, A[0][0], 0, 0, 0);
        A[0][1] = __builtin_amdgcn_mfma_f32_16x16x32_f16(xv00, b10, A[0][1], 0, 0, 0);
        A[1][0] = __builtin_amdgcn_mfma_f32_16x16x32_f16(xv10, b00, A[1][0], 0, 0, 0);
        A[1][1] = __builtin_amdgcn_mfma_f32_16x16x32_f16(xv10, b10, A[1][1], 0, 0, 0);
        A[0][0] = __builtin_amdgcn_mfma_f32_16x16x32_f16(xv01, b01, A[0][0], 0, 0, 0);
        A[0][1] = __builtin_amdgcn_mfma_f32_16x16x32_f16(xv01, b11, A[0][1], 0, 0, 0);
        A[1][0] = __builtin_amdgcn_mfma_f32_16x16x32_f16(xv11, b01, A[1][0], 0, 0, 0);
        A[1][1] = __builtin_amdgcn_mfma_f32_16x16x32_f16(xv11, b11, A[1][1], 0, 0, 0);
    }

    if (MODE == 0) {
        float* op = (float*)outp;
        #pragma unroll
        for (int mt = 0; mt < 2; ++mt) {
            #pragma unroll
            for (int nj = 0; nj < 2; ++nj) {
                const int e = e0 + nj*16;
                #pragma unroll
                for (int r = 0; r < 4; ++r) {
                    int t = t0 + wm*32 + mt*16 + g*4 + r;
                    if (t < NT) op[(size_t)t*64 + e] = A[mt][nj][r];
                }
            }
        }
    } else {
        const float KSC = 0.35355339059327373f * 1.4426950408889634f;
        const float scl = (br == 1) ? KSC : 1.f;
        const int bt0 = t0 / NN;
        const int bound = (bt0 + 1)*NN;
        _Float16* op = (_Float16*)outp;
        #pragma unroll
        for (int mt = 0; mt < 2; ++mt) {
            #pragma unroll
            for (int nj = 0; nj < 2; ++nj) {
                const int e = e0 + nj*16;
                const int hh = e >> 3, dd = e & 7;
                #pragma unroll
                for (int r = 0; r < 4; ++r) {
                    int t = t0 + wm*32 + mt*16 + g*4 + r;
                    if (t < NT) {
                        int bt = (t >= bound) ? bt0 + 1 : bt0;
                        int n = t - bt*NN;
                        size_t pidx = ((size_t)(bt*8 + hh)*NR + n)*8 + dd;
                        op[pidx] = (_Float16)(A[mt][nj][r]*scl);
                    }
                }
            }
        }
    }
}

// ---------------- fused temporal attention + out-proj + residual + LN.
// v2: out-proj y split into 4 independent FMA chains (depth 64 -> 16). ----------------
__global__ __launch_bounds__(256)
void temporal_fused(const float* __restrict__ qg, const float* __restrict__ kg,
                    const float* __restrict__ vg, const float* __restrict__ xres,
                    const float* __restrict__ Wo, const float* __restrict__ gamma,
                    const float* __restrict__ beta, float* __restrict__ xout) {
    const int wid = threadIdx.x >> 6, lane = threadIdx.x & 63;
    const int token = blockIdx.x*4 + wid;
    if (token >= NT) return;
    const int n = token % NN;
    const int b = token / (NN*TT);
    const float scale = 0.35355339059327373f;
    const float qv = qg[(size_t)token*64 + lane] * scale;

    float s[TT], v[TT];
    #pragma unroll
    for (int kt = 0; kt < TT; ++kt) {
        size_t base = ((size_t)(b*TT + kt)*NN + n)*64 + lane;
        float kv = kg[base];
        v[kt] = vg[base];
        float d = qv * kv;
        d += __shfl_xor(d, 1, 64);
        d += __shfl_xor(d, 2, 64);
        d += __shfl_xor(d, 4, 64);
        s[kt] = d;
    }
    float m = s[0];
    #pragma unroll
    for (int kt = 1; kt < TT; ++kt) m = fmaxf(m, s[kt]);
    float l = 0.f, O = 0.f;
    #pragma unroll
    for (int kt = 0; kt < TT; ++kt) {
        float p = __expf(s[kt] - m);
        l += p;
        O += p * v[kt];
    }
    O /= l;
    float y0 = 0.f, y1 = 0.f, y2 = 0.f, y3 = 0.f;
    #pragma unroll
    for (int d = 0; d < 64; d += 4) {
        y0 = fmaf(__shfl(O, d,   64), Wo[(d  )*64 + lane], y0);
        y1 = fmaf(__shfl(O, d+1, 64), Wo[(d+1)*64 + lane], y1);
        y2 = fmaf(__shfl(O, d+2, 64), Wo[(d+2)*64 + lane], y2);
        y3 = fmaf(__shfl(O, d+3, 64), Wo[(d+3)*64 + lane], y3);
    }
    float y = (y0 + y1) + (y2 + y3);
    float r = xres[(size_t)token*64 + lane] + y;
    float mu = wave_reduce_sum(r) * (1.f/64.f);
    float diff = r - mu;
    float var = wave_reduce_sum(diff*diff) * (1.f/64.f);
    xout[(size_t)token*64 + lane] = diff * rsqrtf(var + EPS) * gamma[lane] + beta[lane];
}

// ---------------- spatial attention v13: interleaved KV LDS + register prefetch.
// 8-seg x 32q; grid (192, 11); lane = qu*8 + seg; 41 keys/seg. ----------------
__global__ __launch_bounds__(256)
void spatial_attn13(const _Float16* __restrict__ Qh, const _Float16* __restrict__ Kh,
                    const _Float16* __restrict__ Vh, const unsigned* __restrict__ pmr,
                    _Float16* __restrict__ outs) {
    const int bh = blockIdx.x;
    const int bt = bh >> 3, h = bh & 7;
    const int q0 = blockIdx.y * 32;
    __shared__ _Float16 KV[NR*16];    // [k][0:8)=K row, [k][8:16)=V row
    const int tid = threadIdx.x;
    const _Float16* Kb = Kh + (size_t)bh*NR*8;
    const _Float16* Vb = Vh + (size_t)bh*NR*8;

    for (int u = tid; u < NR; u += 256) {
        *(f16x8*)&KV[u*16]     = *(const f16x8*)&Kb[u*8];
        *(f16x8*)&KV[u*16 + 8] = *(const f16x8*)&Vb[u*8];
    }
    __syncthreads();

    const int wid = tid >> 6, lane = tid & 63;
    const int qu = lane >> 3, seg = lane & 7;
    const int nq = q0 + wid*8 + qu;
    const bool act = nq < NN;
    const int qm = act ? nq : NN-1;

    f16x8 qv = *(const f16x8*)(Qh + ((size_t)bh*NR + qm)*8);
    const f16x2* qh2 = (const f16x2*)&qv;
    const int ks = seg*KPS;

    const size_t mbase = ((size_t)qm*SEGS + seg)*2;
    const size_t mstep = (size_t)NN*SEGS*2;
    unsigned w00 = pmr[mbase],           w01 = pmr[mbase+1];
    unsigned w10 = pmr[mstep+mbase],     w11 = pmr[mstep+mbase+1];
    unsigned w20 = pmr[2*mstep+mbase],   w21 = pmr[2*mstep+mbase+1];

    float l0 = 0.f, l1 = 0.f, l2 = 0.f;
    f32x2 O0[4] = {{0,0},{0,0},{0,0},{0,0}};
    f32x2 O1[4] = {{0,0},{0,0},{0,0},{0,0}};
    f32x2 O2[4] = {{0,0},{0,0},{0,0},{0,0}};

    f16x8 kc = *(const f16x8*)&KV[ks*16];
    f16x8 vc = *(const f16x8*)&KV[ks*16 + 8];

    auto step = [&](int j, unsigned b0, unsigned b1, unsigned b2) {
        f16x8 kn = kc, vn = vc;
        if (j + 1 < KPS) {
            kn = *(const f16x8*)&KV[(ks + j + 1)*16];
            vn = *(const f16x8*)&KV[(ks + j + 1)*16 + 8];
        }
        const f16x2* k2 = (const f16x2*)&kc;
        float d = __builtin_amdgcn_fdot2(qh2[0], k2[0], -32.f, false);
        d = __builtin_amdgcn_fdot2(qh2[1], k2[1], d, false);
        d = __builtin_amdgcn_fdot2(qh2[2], k2[2], d, false);
        d = __builtin_amdgcn_fdot2(qh2[3], k2[3], d, false);
        float E = EXP2F(d);
        float E0 = b0 ? E : 0.f;
        float E1 = b1 ? E : 0.f;
        float E2 = b2 ? E : 0.f;
        l0 += E0; l1 += E1; l2 += E2;
        f32x2 e0 = {E0, E0}, e1 = {E1, E1}, e2 = {E2, E2};
        #pragma unroll
        for (int jj = 0; jj < 4; ++jj) {
            f32x2 vp = {(float)vc[2*jj], (float)vc[2*jj+1]};
            O0[jj] += e0 * vp;
            O1[jj] += e1 * vp;
            O2[jj] += e2 * vp;
        }
        kc = kn; vc = vn;
    };
    #pragma unroll
    for (int j = 0; j < 32; ++j)
        step(j, (w00 >> j) & 1u, (w10 >> j) & 1u, (w20 >> j) & 1u);
    #pragma unroll
    for (int j = 32; j < KPS; ++j)
        step(j, (w01 >> (j-32)) & 1u, (w11 >> (j-32)) & 1u, (w21 >> (j-32)) & 1u);

    #pragma unroll
    for (int off = 1; off <= 4; off <<= 1) {
        l0 += __shfl_xor(l0, off, 64);
        l1 += __shfl_xor(l1, off, 64);
        l2 += __shfl_xor(l2, off, 64);
        #pragma unroll
        for (int j = 0; j < 4; ++j) {
            #pragma unroll
            for (int c = 0; c < 2; ++c) {
                O0[j][c] += __shfl_xor(O0[j][c], off, 64);
                O1[j][c] += __shfl_xor(O1[j][c], off, 64);
                O2[j][c] += __shfl_xor(O2[j][c], off, 64);
            }
        }
    }

    if (act && seg == 0) {
        float i0 = 1.f/l0, i1 = 1.f/l1, i2 = 1.f/l2;
        _Float16* op = outs + (size_t)(bt*NN + nq)*192 + h*8;
        f16x8 o0, o1, o2;
        #pragma unroll
        for (int j = 0; j < 4; ++j) {
            o0[2*j] = (_Float16)(O0[j][0]*i0); o0[2*j+1] = (_Float16)(O0[j][1]*i0);
            o1[2*j] = (_Float16)(O1[j][0]*i1); o1[2*j+1] = (_Float16)(O1[j][1]*i1);
            o2[2*j] = (_Float16)(O2[j][0]*i2); o2[2*j+1] = (_Float16)(O2[j][1]*i2);
        }
        *(f16x8*)(op)       = o0;
        *(f16x8*)(op + 64)  = o1;
        *(f16x8*)(op + 128) = o2;
    }
}

// ---------------- spatial proj + residual + LN; a f16 [t][i][64], Wo rows d*3+i.
// v3: scalar a-loads; 6 parallel FMA chains (depth 32). ----------------
__global__ __launch_bounds__(256)
void proj_res_ln_s_kernel(const _Float16* __restrict__ a, const float* __restrict__ xres,
                          const float* __restrict__ Wo, const float* __restrict__ gamma,
                          const float* __restrict__ beta, float* __restrict__ xout) {
    const int wid = threadIdx.x >> 6, lane = threadIdx.x & 63;
    const int token = blockIdx.x*4 + wid;
    if (token >= NT) return;
    const int tu = __builtin_amdgcn_readfirstlane(token);
    const unsigned* aw = (const unsigned*)(a + (size_t)tu*192);  // 96 dwords: 3 rows x 32
    float y0l = 0.f, y1l = 0.f, y2l = 0.f, y0h = 0.f, y1h = 0.f, y2h = 0.f;
    #pragma unroll
    for (int dd = 0; dd < 32; ++dd) {
        unsigned w0 = aw[dd], w1 = aw[32+dd], w2 = aw[64+dd];   // scalar (uniform) loads
        const float* W0 = Wo + (size_t)(6*dd)*64 + lane;        // rows 6dd..6dd+5
        y0l = fmaf(h2f(w0 & 0xffffu), W0[0],   y0l);
        y1l = fmaf(h2f(w1 & 0xffffu), W0[64],  y1l);
        y2l = fmaf(h2f(w2 & 0xffffu), W0[128], y2l);
        y0h = fmaf(h2f(w0 >> 16),     W0[192], y0h);
        y1h = fmaf(h2f(w1 >> 16),     W0[256], y1h);
        y2h = fmaf(h2f(w2 >> 16),     W0[320], y2h);
    }
    float y = ((y0l + y0h) + (y1l + y1h)) + (y2l + y2h);
    float r = xres[(size_t)token*64 + lane] + y;
    float mu = wave_reduce_sum(r) * (1.f/64.f);
    float diff = r - mu;
    float var = wave_reduce_sum(diff*diff) * (1.f/64.f);
    xout[(size_t)token*64 + lane] = diff * rsqrtf(var + EPS) * gamma[lane] + beta[lane];
}

// ---------------- fused tail (module 3): proj_s+LN, FFN0+LN, FFN1+LN -> out.
// v3: scalar a-loads, 6 chains in proj; FFN hs chains split x4, y2b split x2. ----------------
__global__ __launch_bounds__(256)
void tail_fused(const _Float16* __restrict__ a, const float* __restrict__ xres,
                const float* __restrict__ Wo,
                const float* __restrict__ W1a, const float* __restrict__ W2a,
                const float* __restrict__ W1b, const float* __restrict__ W2b,
                const float* __restrict__ ln_g, const float* __restrict__ ln_b,
                float* __restrict__ out) {
    const int wid = threadIdx.x >> 6, lane = threadIdx.x & 63;
    const int token = blockIdx.x*4 + wid;
    if (token >= NT) return;
    const int c = lane & 15;

    const int tu = __builtin_amdgcn_readfirstlane(token);
    const unsigned* aw = (const unsigned*)(a + (size_t)tu*192);  // 96 dwords: 3 rows x 32
    float y0l = 0.f, y1l = 0.f, y2l = 0.f, y0h = 0.f, y1h = 0.f, y2h = 0.f;
    #pragma unroll
    for (int dd = 0; dd < 32; ++dd) {
        unsigned w0 = aw[dd], w1 = aw[32+dd], w2 = aw[64+dd];   // scalar (uniform) loads
        const float* W0 = Wo + (size_t)(6*dd)*64 + lane;        // rows 6dd..6dd+5
        y0l = fmaf(h2f(w0 & 0xffffu), W0[0],   y0l);
        y1l = fmaf(h2f(w1 & 0xffffu), W0[64],  y1l);
        y2l = fmaf(h2f(w2 & 0xffffu), W0[128], y2l);
        y0h = fmaf(h2f(w0 >> 16),     W0[192], y0h);
        y1h = fmaf(h2f(w1 >> 16),     W0[256], y1h);
        y2h = fmaf(h2f(w2 >> 16),     W0[320], y2h);
    }
    float y = ((y0l + y0h) + (y1l + y1h)) + (y2l + y2h);
    float r = xres[(size_t)token*64 + lane] + y;
    float mu = wave_reduce_sum(r) * (1.f/64.f);
    float diff = r - mu;
    float var = wave_reduce_sum(diff*diff) * (1.f/64.f);
    float x1 = diff * rsqrtf(var + EPS) * ln_g[lane] + ln_b[lane];

    float h0 = 0.f, h1 = 0.f, h2 = 0.f, h3 = 0.f;
    #pragma unroll
    for (int d = 0; d < 64; d += 4) {
        h0 = fmaf(__shfl(x1, d,   64), W1a[(d  )*16 + c], h0);
        h1 = fmaf(__shfl(x1, d+1, 64), W1a[(d+1)*16 + c], h1);
        h2 = fmaf(__shfl(x1, d+2, 64), W1a[(d+2)*16 + c], h2);
        h3 = fmaf(__shfl(x1, d+3, 64), W1a[(d+3)*16 + c], h3);
    }
    float hr = fmaxf((h0 + h1) + (h2 + h3), 0.f);
    float ya = 0.f, yb = 0.f;
    #pragma unroll
    for (int cc = 0; cc < 16; cc += 2) {
        ya = fmaf(__shfl(hr, cc,   64), W2a[(cc  )*64 + lane], ya);
        yb = fmaf(__shfl(hr, cc+1, 64), W2a[(cc+1)*64 + lane], yb);
    }
    r = x1 + (ya + yb);
    mu = wave_reduce_sum(r) * (1.f/64.f);
    diff = r - mu;
    var = wave_reduce_sum(diff*diff) * (1.f/64.f);
    float x2 = diff * rsqrtf(var + EPS) * ln_g[64 + lane] + ln_b[64 + lane];

    h0 = 0.f; h1 = 0.f; h2 = 0.f; h3 = 0.f;
    #pragma unroll
    for (int d = 0; d < 64; d += 4) {
        h0 = fmaf(__shfl(x2, d,   64), W1b[(d  )*16 + c], h0);
        h1 = fmaf(__shfl(x2, d+1, 64), W1b[(d+1)*16 + c], h1);
        h2 = fmaf(__shfl(x2, d+2, 64), W1b[(d+2)*16 + c], h2);
        h3 = fmaf(__shfl(x2, d+3, 64), W1b[(d+3)*16 + c], h3);
    }
    hr = fmaxf((h0 + h1) + (h2 + h3), 0.f);
    ya = 0.f; yb = 0.f;
    #pragma unroll
    for (int cc = 0; cc < 16; cc += 2) {
        ya = fmaf(__shfl(hr, cc,   64), W2b[(cc  )*64 + lane], ya);
        yb = fmaf(__shfl(hr, cc+1, 64), W2b[(cc+1)*64 + lane], yb);
    }
    r = x2 + (ya + yb);
    mu = wave_reduce_sum(r) * (1.f/64.f);
    diff = r - mu;
    var = wave_reduce_sum(diff*diff) * (1.f/64.f);
    out[(size_t)token*64 + lane] = diff * rsqrtf(var + EPS) * ln_g[128 + lane] + ln_b[128 + lane];
}

// ---------------- launcher ----------------
extern "C" void kernel_launch(void* const* d_in, const int* in_sizes, int n_in,
                              void* d_out, int out_size, void* d_ws, size_t ws_size,
                              hipStream_t stream) {
    const float* queries = (const float*)d_in[0];
    const float* keys    = (const float*)d_in[1];
    const float* values  = (const float*)d_in[2];
    const float* ste_q   = (const float*)d_in[3];
    const float* ste_k   = (const float*)d_in[4];
    const float* ste_v   = (const float*)d_in[5];
    const int*   tms     = (const int*)d_in[6];
    const float* mW1     = (const float*)d_in[7];
    const float* mb1     = (const float*)d_in[8];
    const float* mW2     = (const float*)d_in[9];
    const float* mb2     = (const float*)d_in[10];
    const float* Wo_t    = (const float*)d_in[11];
    const float* Wo_s    = (const float*)d_in[12];
    const float* ffn_W1  = (const float*)d_in[13];
    const float* ffn_W2  = (const float*)d_in[14];
    const float* ln_g    = (const float*)d_in[15];
    const float* ln_b    = (const float*)d_in[16];

    char* p = (char*)d_ws;
    auto carve = [&](size_t bytes) { char* r = p; p += (bytes + 255) & ~(size_t)255; return r; };
    float* xbuf = (float*)carve((size_t)NT64*4);
    float* qg   = (float*)carve((size_t)NT64*4);
    float* kg   = (float*)carve((size_t)NT64*4);
    float* vg   = (float*)carve((size_t)NT64*4);
    _Float16* as_ = (_Float16*)carve((size_t)NT*192*2);
    _Float16* Wt  = (_Float16*)carve((size_t)12*64*KTOT*2);
    _Float16* W1f = (_Float16*)carve((size_t)12*4096*2);
    unsigned* pmr = (unsigned*)carve((size_t)MM*NN*SEGS*2*4);
    _Float16* Qh  = (_Float16*)carve((size_t)BB*TT*HH*NR*8*2);
    _Float16* Kh  = (_Float16*)carve((size_t)BB*TT*HH*NR*8*2);
    _Float16* Vh  = (_Float16*)carve((size_t)BB*TT*HH*NR*8*2);

    const dim3 blk(256);
    const dim3 g_tok(NT/4);
    const dim3 g_sa(BB*TT*HH, 11);
    const dim3 g_gemm((NT + 63)/64, 3);

    // one-time prep (merged): 780 Wt blocks + 12 W1 blocks + 31 mask blocks
    prep_all<<<dim3(823), blk, 0, stream>>>(mW2, mb2, Wt, mW1, W1f, tms, pmr);

    // ---- module 0: temporal on (queries, keys, values), residual = queries ----
    meta_gemm_t<0><<<g_gemm, blk, 0, stream>>>(
        queries, keys, values, ste_q, ste_k, ste_v,
        W1f, mb1, Wt, (void*)qg, (void*)kg, (void*)vg);
    temporal_fused<<<g_tok, blk, 0, stream>>>(
        qg, kg, vg, queries, Wo_t, ln_g, ln_b, xbuf);

    // ---- module 1: spatial on x ----
    meta_gemm_t<1><<<g_gemm, blk, 0, stream>>>(
        xbuf, xbuf, xbuf, ste_q, ste_k, ste_v,
        W1f + (size_t)3*4096, mb1 + (size_t)3*64, Wt + (size_t)3*64*KTOT,
        (void*)Qh, (void*)Kh, (void*)Vh);
    spatial_attn13<<<g_sa, blk, 0, stream>>>(Qh, Kh, Vh, pmr, as_);
    proj_res_ln_s_kernel<<<g_tok, blk, 0, stream>>>(
        as_, xbuf, Wo_s, ln_g + 64, ln_b + 64, xbuf);

    // ---- module 2: temporal on x ----
    meta_gemm_t<0><<<g_gemm, blk, 0, stream>>>(
        xbuf, xbuf, xbuf, ste_q, ste_k, ste_v,
        W1f + (size_t)6*4096, mb1 + (size_t)6*64, Wt + (size_t)6*64*KTOT,
        (void*)qg, (void*)kg, (void*)vg);
    temporal_fused<<<g_tok, blk, 0, stream>>>(
        qg, kg, vg, xbuf, Wo_t + (size_t)64*64, ln_g + 128, ln_b + 128, xbuf);

    // ---- module 3: spatial on x + fused tail ----
    meta_gemm_t<1><<<g_gemm, blk, 0, stream>>>(
        xbuf, xbuf, xbuf, ste_q, ste_k, ste_v,
        W1f + (size_t)9*4096, mb1 + (size_t)9*64, Wt + (size_t)9*64*KTOT,
        (void*)Qh, (void*)Kh, (void*)Vh);
    spatial_attn13<<<g_sa, blk, 0, stream>>>(Qh, Kh, Vh, pmr, as_);
    tail_fused<<<g_tok, blk, 0, stream>>>(
        as_, xbuf, Wo_s + (size_t)192*64,
        ffn_W1, ffn_W2, ffn_W1 + (size_t)64*16, ffn_W2 + (size_t)16*64,
        ln_g + 192, ln_b + 192, (float*)d_out);
}